// Round 1
// 811.213 us; speedup vs baseline: 1.2380x; 1.2380x over previous
//
#include <hip/hip_runtime.h>
#include <hip/hip_bf16.h>
#include <math.h>

// MLA attention forward, bf16 MFMA (round 4: attention staging via global_load_lds
// with pre-swizzled source, split K/V prefetch pipeline, setprio, longest-first +
// XCD-grouped dispatch).
#define BB 2
#define SS 2048
#define HH 4096
#define NHEADS 32
#define HDIM 128
#define VDIM 128
#define QRANK 1536
#define KVRANK 512
#define MROWS (BB * SS) /* 4096 */

typedef unsigned short u16;
typedef unsigned int u32;
typedef short short8 __attribute__((ext_vector_type(8)));   // 8 bf16 (4 VGPRs)
typedef float floatx4 __attribute__((ext_vector_type(4)));

#if __has_builtin(__builtin_amdgcn_exp2f)
__device__ __forceinline__ float fast_exp2(float x) { return __builtin_amdgcn_exp2f(x); }
#else
__device__ __forceinline__ float fast_exp2(float x) { return exp2f(x); }
#endif

// fp32 -> bf16 (RNE)
__device__ __forceinline__ u16 f2bf(float f) {
    u32 u = __float_as_uint(f);
    u += 0x7fffu + ((u >> 16) & 1u);
    return (u16)(u >> 16);
}

// async global->LDS, 16 bytes per lane
#define GLD16(gp, lp)                                                        \
    __builtin_amdgcn_global_load_lds(                                        \
        (const __attribute__((address_space(1))) void*)(gp),                 \
        (__attribute__((address_space(3))) void*)(lp), 16, 0, 0)

// ---------------------------------------------------------------------------
// fp32 -> bf16 convert
// ---------------------------------------------------------------------------
__global__ __launch_bounds__(256) void cvt_bf16(const float* __restrict__ in,
                                                u16* __restrict__ out, int n4) {
    int idx = blockIdx.x * 256 + threadIdx.x;
    int stride = gridDim.x * 256;
    for (int i = idx; i < n4; i += stride) {
        float4 f = ((const float4*)in)[i];
        u32 lo = (u32)f2bf(f.x) | ((u32)f2bf(f.y) << 16);
        u32 hi = (u32)f2bf(f.z) | ((u32)f2bf(f.w) << 16);
        ((uint2*)out)[i] = make_uint2(lo, hi);
    }
}

// ---------------------------------------------------------------------------
// fp32 [R,C] -> bf16 [C,R] transpose+convert. Grid (C/64, R/64), block 256.
// ---------------------------------------------------------------------------
__global__ __launch_bounds__(256) void transpose_cvt(const float* __restrict__ in,
                                                     u16* __restrict__ out,
                                                     int R, int C) {
    __shared__ u16 T[64][65];
    const int c0 = blockIdx.x * 64, r0 = blockIdx.y * 64;
    const int tx = threadIdx.x & 63, ty = threadIdx.x >> 6;
#pragma unroll
    for (int p = 0; p < 16; ++p) {
        int rr = p * 4 + ty;
        T[rr][tx] = f2bf(in[(size_t)(r0 + rr) * C + c0 + tx]);
    }
    __syncthreads();
#pragma unroll
    for (int p = 0; p < 16; ++p) {
        int cc = p * 4 + ty;
        out[(size_t)(c0 + cc) * R + r0 + tx] = T[tx][cc];
    }
}

// ---------------------------------------------------------------------------
// v [B*S, :] (row stride ldin, col offset applied by caller) bf16
//   -> vt [(b,h), 128, 2048]. Grid (S/64, VD/64, B*NH), block 256.
// ---------------------------------------------------------------------------
__global__ __launch_bounds__(256) void transpose_v(const u16* __restrict__ in, int ldin,
                                                   u16* __restrict__ out) {
    __shared__ u16 T[64][65];
    const int s0 = blockIdx.x * 64, d0 = blockIdx.y * 64;
    const int bh = blockIdx.z, b = bh >> 5, h = bh & 31;
    const int tx = threadIdx.x & 63, ty = threadIdx.x >> 6;
#pragma unroll
    for (int p = 0; p < 16; ++p) {
        int ss = p * 4 + ty;
        T[ss][tx] = in[(size_t)(b * SS + s0 + ss) * ldin + h * 128 + d0 + tx];
    }
    __syncthreads();
#pragma unroll
    for (int p = 0; p < 16; ++p) {
        int dd = p * 4 + ty;
        out[((size_t)bh * 128 + d0 + dd) * SS + s0 + tx] = T[tx][dd];
    }
}

// ---------------------------------------------------------------------------
// bf16 MFMA GEMM: C[M,N] = A[M,K](lda) @ Bt[N,K](ldb)^T.
// MODE 0: fp32 Cf(ldf). MODE 1: bf16 Cb(ldc).
// MODE 3: bf16 Cb(ldc) full + fp32 Cf(ldf) for cols >= nsplit (col-nsplit).
// ---------------------------------------------------------------------------
template <int MODE>
__global__ __launch_bounds__(256) void gemm_bt(const u16* __restrict__ A, int lda,
                                               const u16* __restrict__ Bt, int ldb,
                                               float* __restrict__ Cf, int ldf,
                                               u16* __restrict__ Cb, int ldc,
                                               int M, int N, int K, int nsplit) {
    __shared__ __align__(16) u16 As[128 * 32];
    __shared__ __align__(16) u16 Bs[128 * 32];

    const int tid = threadIdx.x;
    const int bm0 = blockIdx.y * 128, bn0 = blockIdx.x * 128;
    const int w = tid >> 6, lane = tid & 63;
    const int lo = lane & 15, quad = lane >> 4;
    const int wm = (w & 1) * 64, wn = (w >> 1) * 64;

    floatx4 acc[4][4];
#pragma unroll
    for (int i = 0; i < 4; ++i)
#pragma unroll
        for (int j = 0; j < 4; ++j) acc[i][j] = (floatx4){0.f, 0.f, 0.f, 0.f};

    const int o0 = tid * 16, o1 = tid * 16 + 4096;
    const int ar0 = o0 >> 6, ak0 = (o0 & 63) >> 1;
    const int ar1 = o1 >> 6, ak1 = (o1 & 63) >> 1;
    const u16* Ab = A + (size_t)bm0 * lda;
    const u16* Bb = Bt + (size_t)bn0 * ldb;

    for (int k0 = 0; k0 < K; k0 += 32) {
        GLD16(Ab + (size_t)ar0 * lda + k0 + ak0, &As[o0 >> 1]);
        GLD16(Ab + (size_t)ar1 * lda + k0 + ak1, &As[o1 >> 1]);
        GLD16(Bb + (size_t)ar0 * ldb + k0 + ak0, &Bs[o0 >> 1]);
        GLD16(Bb + (size_t)ar1 * ldb + k0 + ak1, &Bs[o1 >> 1]);
        asm volatile("s_waitcnt vmcnt(0)" ::: "memory");
        __syncthreads();

        short8 af[4], bfr[4];
#pragma unroll
        for (int i = 0; i < 4; ++i)
            af[i] = *(const short8*)&As[(wm + i * 16 + lo) * 32 + quad * 8];
#pragma unroll
        for (int j = 0; j < 4; ++j)
            bfr[j] = *(const short8*)&Bs[(wn + j * 16 + lo) * 32 + quad * 8];
#pragma unroll
        for (int i = 0; i < 4; ++i)
#pragma unroll
            for (int j = 0; j < 4; ++j)
                acc[i][j] = __builtin_amdgcn_mfma_f32_16x16x32_bf16(af[i], bfr[j], acc[i][j], 0, 0, 0);
        __syncthreads();
    }

#pragma unroll
    for (int i = 0; i < 4; ++i) {
#pragma unroll
        for (int j = 0; j < 4; ++j) {
            const int row = bm0 + wm + i * 16 + quad * 4;
            const int col = bn0 + wn + j * 16 + lo;
#pragma unroll
            for (int r = 0; r < 4; ++r) {
                float v = acc[i][j][r];
                if (MODE == 0) Cf[(size_t)(row + r) * ldf + col] = v;
                if (MODE == 1) Cb[(size_t)(row + r) * ldc + col] = f2bf(v);
                if (MODE == 3) {
                    Cb[(size_t)(row + r) * ldc + col] = f2bf(v);
                    if (col >= nsplit) Cf[(size_t)(row + r) * ldf + (col - nsplit)] = v;
                }
            }
        }
    }
}

// ---------------------------------------------------------------------------
// MFMA flash attention (causal), Q-tile 128 rows/block (wave owns 32 rows),
// K-tile 64 keys. Single-pass softmax (scores bounded; no max shift),
// l computed via 16 ones-columns appended to V^T (pure MFMA, no shuffles).
//
// Staging: global_load_lds (16B/lane) directly into linear LDS; the XOR bank
// swizzle (involution) is applied to the per-lane GLOBAL source address, so
// LDS contents are byte-identical to the old reg-staged path.
// Pipeline: K(kt+1) issued after the mid-tile barrier (covered by PV),
// V(kt+1) issued after the end barrier (covered by next QK+softmax). The
// vmcnt(0) embedded in each __syncthreads drains loads that have had ~half a
// tile of MFMA to land, instead of a cold stall at the head of every tile.
//
// q: bf16 [B*S, 4096] (ldq=HH); k: bf16 rows stride ldk; vt [(bh),128,2048];
// ao: bf16 [B*S, 4096]. Grid (64, 16): x=bh (same-bh blocks 64 apart -> same
// XCD -> K/V stays in one L2), y=qt reversed (all longest blocks dispatch first).
// ---------------------------------------------------------------------------
__global__ __launch_bounds__(256) void mla_attn_mfma(const u16* __restrict__ qm,
                                                     const u16* __restrict__ km, int ldk,
                                                     const u16* __restrict__ vt,
                                                     u16* __restrict__ ao) {
    __shared__ __align__(16) u16 Ks[64 * 128];        // [key][hd], chunk ^= key&15
    __shared__ __align__(16) u16 Vt[(128 + 16) * 64]; // [vd][key], chunk ^= vd&7; rows 128..143 = 1.0
    __shared__ __align__(16) u16 Ps[128 * 68];        // [q][key], stride 68 (conflict-free)

    const int qt = 15 - blockIdx.y;  // reversed: longest blocks dispatch first
    const int bh = blockIdx.x;
    const int b = bh >> 5, h = bh & 31;
    const int tid = threadIdx.x;
    const int w = tid >> 6, lane = tid & 63;
    const int lo = lane & 15, quad = lane >> 4;
    const int q0 = qt * 128;

    const float SCALE_L2E = 0.08838834764831845f * 1.4426950408889634f;

    // ones rows (vd 128..143) for the l-column trick: 16*64 u16 = 512 u32
    {
        u32* p = (u32*)&Vt[128 * 64];
        for (int i = tid; i < 512; i += 256) p[i] = 0x3F803F80u;
    }

    const u16* kbase = km + (size_t)(b * SS) * ldk + h * 128;
    const u16* vtbase = vt + (size_t)bh * 128 * SS;
    const int nkt = 2 * qt + 2;

    // per-thread staging constants: linear LDS dest (o bytes), pre-swizzled
    // global source offsets (XOR involution == the read-side swizzle)
    int ol_[4], kgo[4], vgo[4];
#pragma unroll
    for (int p = 0; p < 4; ++p) {
        int o = tid * 16 + p * 4096;           // byte offset within 16KB tile
        int key = o >> 8, ch = (o & 255) >> 4; // K row, 16B chunk
        kgo[p] = key * ldk + ((ch ^ (key & 15)) << 3);
        int d = o >> 7, ch2 = (o & 127) >> 4;  // V row, 16B chunk
        vgo[p] = d * SS + ((ch2 ^ (d & 7)) << 3);
        ol_[p] = o >> 1;                       // u16 index (linear LDS)
    }

    // prologue: stage tile 0 (K and V) directly to LDS
#pragma unroll
    for (int p = 0; p < 4; ++p) GLD16(kbase + kgo[p], &Ks[ol_[p]]);
#pragma unroll
    for (int p = 0; p < 4; ++p) GLD16(vtbase + vgo[p], &Vt[ol_[p]]);

    // Q fragments: wave w owns q rows w*32 + mf*16 + lo
    short8 qf[2][4];
#pragma unroll
    for (int mf = 0; mf < 2; ++mf) {
        const u16* qrow = qm + (size_t)(b * SS + q0 + w * 32 + mf * 16 + lo) * HH + h * 128;
#pragma unroll
        for (int ks = 0; ks < 4; ++ks) qf[mf][ks] = *(const short8*)(qrow + ks * 32 + quad * 8);
    }

    floatx4 oacc[2][8], olv[2];
#pragma unroll
    for (int mf = 0; mf < 2; ++mf) {
        olv[mf] = (floatx4){0.f, 0.f, 0.f, 0.f};
#pragma unroll
        for (int n = 0; n < 8; ++n) oacc[mf][n] = (floatx4){0.f, 0.f, 0.f, 0.f};
    }

    __syncthreads();  // tile 0 staged (embedded vmcnt(0) drains the GLDs)

    for (int kt = 0; kt < nkt; ++kt) {
        const bool need_mask = (kt >= nkt - 2);
        const bool notlast = (kt + 1 < nkt);

        // ---- QK^T + softmax -> Ps (reads Ks only) ----
#pragma unroll
        for (int mf = 0; mf < 2; ++mf) {
            floatx4 s[4];
#pragma unroll
            for (int nf = 0; nf < 4; ++nf) s[nf] = (floatx4){0.f, 0.f, 0.f, 0.f};
            __builtin_amdgcn_s_setprio(1);
#pragma unroll
            for (int nf = 0; nf < 4; ++nf)
#pragma unroll
                for (int ks = 0; ks < 4; ++ks) {
                    short8 kf = *(const short8*)&Ks[(nf * 16 + lo) * 128 + (((ks * 4 + quad) ^ lo) << 3)];
                    s[nf] = __builtin_amdgcn_mfma_f32_16x16x32_bf16(qf[mf][ks], kf, s[nf], 0, 0, 0);
                }
            __builtin_amdgcn_s_setprio(0);
            // P = exp2(s*scale) (bounded scores: no max shift), masked -> 0
#pragma unroll
            for (int nf = 0; nf < 4; ++nf)
#pragma unroll
                for (int r = 0; r < 4; ++r) {
                    float p = fast_exp2(s[nf][r] * SCALE_L2E);
                    if (need_mask) {
                        int kgi = kt * 64 + nf * 16 + lo;
                        int qg = q0 + w * 32 + mf * 16 + quad * 4 + r;
                        p = (kgi <= qg) ? p : 0.f;
                    }
                    Ps[(w * 32 + mf * 16 + quad * 4 + r) * 68 + nf * 16 + lo] = f2bf(p);
                }
        }

        __syncthreads();  // all waves done reading Ks; drains V(kt) prefetch too

        // prefetch K(kt+1) into Ks — lands under the PV phase below
        if (notlast) {
            const u16* kn = kbase + (size_t)(kt + 1) * 64 * ldk;
#pragma unroll
            for (int p = 0; p < 4; ++p) GLD16(kn + kgo[p], &Ks[ol_[p]]);
        }

        // ---- PV + l (reads Vt + own Ps rows; same-wave Ps dep only) ----
#pragma unroll
        for (int mf = 0; mf < 2; ++mf) {
            short8 pa[2];
#pragma unroll
            for (int ks2 = 0; ks2 < 2; ++ks2)
                pa[ks2] = *(const short8*)&Ps[(w * 32 + mf * 16 + lo) * 68 + ks2 * 32 + quad * 8];
            __builtin_amdgcn_s_setprio(1);
#pragma unroll
            for (int n = 0; n < 8; ++n)
#pragma unroll
                for (int ks2 = 0; ks2 < 2; ++ks2) {
                    short8 vf = *(const short8*)&Vt[(n * 16 + lo) * 64 + (((ks2 * 4 + quad) ^ (lo & 7)) << 3)];
                    oacc[mf][n] = __builtin_amdgcn_mfma_f32_16x16x32_bf16(pa[ks2], vf, oacc[mf][n], 0, 0, 0);
                }
#pragma unroll
            for (int ks2 = 0; ks2 < 2; ++ks2) {
                short8 vf = *(const short8*)&Vt[(128 + lo) * 64 + (((ks2 * 4 + quad) ^ (lo & 7)) << 3)];
                olv[mf] = __builtin_amdgcn_mfma_f32_16x16x32_bf16(pa[ks2], vf, olv[mf], 0, 0, 0);
            }
            __builtin_amdgcn_s_setprio(0);
        }

        __syncthreads();  // all waves done reading Vt; drains K(kt+1) prefetch

        // prefetch V(kt+1) into Vt — lands under the next QK+softmax phase
        if (notlast) {
            const u16* vn = vtbase + (size_t)(kt + 1) * 64;
#pragma unroll
            for (int p = 0; p < 4; ++p) GLD16(vn + vgo[p], &Vt[ol_[p]]);
        }
    }

    // epilogue: O / l
#pragma unroll
    for (int mf = 0; mf < 2; ++mf) {
        u16* obase = ao + (size_t)(b * SS + q0 + w * 32 + mf * 16 + quad * 4) * HH + h * 128;
#pragma unroll
        for (int r = 0; r < 4; ++r) {
            float inv = 1.f / olv[mf][r];
#pragma unroll
            for (int n = 0; n < 8; ++n)
                obase[(size_t)r * HH + n * 16 + lo] = f2bf(oacc[mf][n][r] * inv);
        }
    }
}

// ---------------------------------------------------------------------------
// Orchestration. ws layout (u16 elements):
//   hs_bf @0 (16.8M)            -> vt aliases after GF1
//   q_bf @16777216 (16.8M)
//   kv_bf @33554432 (33.55M)    [4096][8192]: k cols 0..4095, v cols 4096..8191
//   ao_bf @67108864 (16.8M)
//   wqa_kvaT @83886080 (8.39M)  [2048][4096]: w_qaT rows 0..1535, w_kvaT rows 1536..2047
//   w_qbT @92274688 (6.29M)
//   wkv_bT @98566144 (4.19M)    [8192][512]: w_kbT rows 0..4095, w_vbT rows 4096..8191
//   w_oT @102760448 (16.8M)
//   qc_ckv @119537664 (8.39M)   [4096][2048]: q_c cols 0..1535, ckv cols 1536..2047
// Total 255.9 MB.
// ---------------------------------------------------------------------------
extern "C" void kernel_launch(void* const* d_in, const int* in_sizes, int n_in,
                              void* d_out, int out_size, void* d_ws, size_t ws_size,
                              hipStream_t stream) {
    const float* hs    = (const float*)d_in[0];
    const float* w_qa  = (const float*)d_in[1];
    const float* w_qb  = (const float*)d_in[2];
    const float* w_kva = (const float*)d_in[3];
    const float* w_kb  = (const float*)d_in[4];
    const float* w_vb  = (const float*)d_in[5];
    const float* w_o   = (const float*)d_in[6];

    float* out   = (float*)d_out;
    float* ckv_f = out + (size_t)MROWS * HH;

    u16* ws = (u16*)d_ws;
    u16* hs_bf    = ws;
    u16* vt       = ws;                       // aliases hs_bf (dead after GF1)
    u16* q_bf     = ws + 16777216ull;
    u16* kv_bf    = ws + 33554432ull;         // [4096][8192]
    u16* ao_bf    = ws + 67108864ull;
    u16* wqa_kvaT = ws + 83886080ull;         // [2048][4096]
    u16* w_qbT    = ws + 92274688ull;
    u16* wkv_bT   = ws + 98566144ull;         // [8192][512]
    u16* w_oT     = ws + 102760448ull;
    u16* qc_ckv   = ws + 119537664ull;        // [4096][2048]

    dim3 blk(256);

    cvt_bf16<<<2048, blk, 0, stream>>>(hs, hs_bf, (MROWS * HH) / 4);
    transpose_cvt<<<dim3(QRANK / 64, HH / 64), blk, 0, stream>>>(w_qa, wqa_kvaT, HH, QRANK);
    transpose_cvt<<<dim3(KVRANK / 64, HH / 64), blk, 0, stream>>>(w_kva, wqa_kvaT + 1536ull * 4096, HH, KVRANK);
    transpose_cvt<<<dim3(HH / 64, QRANK / 64), blk, 0, stream>>>(w_qb, w_qbT, QRANK, HH);
    transpose_cvt<<<dim3(HH / 64, KVRANK / 64), blk, 0, stream>>>(w_kb, wkv_bT, KVRANK, HH);
    transpose_cvt<<<dim3(HH / 64, KVRANK / 64), blk, 0, stream>>>(w_vb, wkv_bT + 4096ull * 512, KVRANK, HH);
    transpose_cvt<<<dim3(HH / 64, HH / 64), blk, 0, stream>>>(w_o, w_oT, HH, HH);

    // GF1: [q_c | ckv] = hs @ [w_qa | w_kva]   (N=2048, K=4096); ckv also fp32->d_out
    gemm_bt<3><<<dim3(2048 / 128, MROWS / 128), blk, 0, stream>>>(
        hs_bf, HH, wqa_kvaT, HH, ckv_f, KVRANK, qc_ckv, 2048, MROWS, 2048, HH, QRANK);
    // G2: q = q_c @ w_qb   (K=1536, A lda=2048)
    gemm_bt<1><<<dim3(HH / 128, MROWS / 128), blk, 0, stream>>>(
        qc_ckv, 2048, w_qbT, QRANK, nullptr, 0, q_bf, HH, MROWS, HH, QRANK, 0);
    // GKV: [k | v] = ckv @ [w_kb | w_vb]   (N=8192, K=512, A lda=2048)
    gemm_bt<1><<<dim3(8192 / 128, MROWS / 128), blk, 0, stream>>>(
        qc_ckv + 1536, 2048, wkv_bT, KVRANK, nullptr, 0, kv_bf, 8192, MROWS, 8192, KVRANK, 0);
    // V^T per head (vt aliases dead hs_bf)
    transpose_v<<<dim3(SS / 64, VDIM / 64, BB * NHEADS), blk, 0, stream>>>(kv_bf + 4096, 8192, vt);
    // causal MFMA attention: grid (bh, qt) — longest-first, same-bh on same XCD
    mla_attn_mfma<<<dim3(BB * NHEADS, 16), blk, 0, stream>>>(q_bf, kv_bf, 8192, vt, ao_bf);
    // G7: out = ao @ w_o
    gemm_bt<0><<<dim3(HH / 128, MROWS / 128), blk, 0, stream>>>(
        ao_bf, HH, w_oT, HH, out, HH, nullptr, 0, MROWS, HH, HH, 0);
}

// Round 3
// 799.248 us; speedup vs baseline: 1.2565x; 1.0150x over previous
//
#include <hip/hip_runtime.h>
#include <hip/hip_bf16.h>
#include <math.h>

// MLA attention forward, bf16 MFMA (round 6: resubmit of round-5 structure —
// 256x256-tile BK=32 GEMMs, 4-slot rolling pipeline, counted vmcnt, XOR-swizzled
// LDS — with sched_barrier(0) fences pinning GLD16 issue order around the
// counted s_waitcnt. Attention unchanged from round 4.
#define BB 2
#define SS 2048
#define HH 4096
#define NHEADS 32
#define HDIM 128
#define VDIM 128
#define QRANK 1536
#define KVRANK 512
#define MROWS (BB * SS) /* 4096 */

typedef unsigned short u16;
typedef unsigned int u32;
typedef short short8 __attribute__((ext_vector_type(8)));   // 8 bf16 (4 VGPRs)
typedef float floatx4 __attribute__((ext_vector_type(4)));

#if __has_builtin(__builtin_amdgcn_exp2f)
__device__ __forceinline__ float fast_exp2(float x) { return __builtin_amdgcn_exp2f(x); }
#else
__device__ __forceinline__ float fast_exp2(float x) { return exp2f(x); }
#endif

// fp32 -> bf16 (RNE)
__device__ __forceinline__ u16 f2bf(float f) {
    u32 u = __float_as_uint(f);
    u += 0x7fffu + ((u >> 16) & 1u);
    return (u16)(u >> 16);
}

// async global->LDS, 16 bytes per lane
#define GLD16(gp, lp)                                                        \
    __builtin_amdgcn_global_load_lds(                                        \
        (const __attribute__((address_space(1))) void*)(gp),                 \
        (__attribute__((address_space(3))) void*)(lp), 16, 0, 0)

// ---------------------------------------------------------------------------
// fp32 -> bf16 convert
// ---------------------------------------------------------------------------
__global__ __launch_bounds__(256) void cvt_bf16(const float* __restrict__ in,
                                                u16* __restrict__ out, int n4) {
    int idx = blockIdx.x * 256 + threadIdx.x;
    int stride = gridDim.x * 256;
    for (int i = idx; i < n4; i += stride) {
        float4 f = ((const float4*)in)[i];
        u32 lo = (u32)f2bf(f.x) | ((u32)f2bf(f.y) << 16);
        u32 hi = (u32)f2bf(f.z) | ((u32)f2bf(f.w) << 16);
        ((uint2*)out)[i] = make_uint2(lo, hi);
    }
}

// ---------------------------------------------------------------------------
// fp32 [R,C] -> bf16 [C,R] transpose+convert. Grid (C/64, R/64), block 256.
// ---------------------------------------------------------------------------
__global__ __launch_bounds__(256) void transpose_cvt(const float* __restrict__ in,
                                                     u16* __restrict__ out,
                                                     int R, int C) {
    __shared__ u16 T[64][65];
    const int c0 = blockIdx.x * 64, r0 = blockIdx.y * 64;
    const int tx = threadIdx.x & 63, ty = threadIdx.x >> 6;
#pragma unroll
    for (int p = 0; p < 16; ++p) {
        int rr = p * 4 + ty;
        T[rr][tx] = f2bf(in[(size_t)(r0 + rr) * C + c0 + tx]);
    }
    __syncthreads();
#pragma unroll
    for (int p = 0; p < 16; ++p) {
        int cc = p * 4 + ty;
        out[(size_t)(c0 + cc) * R + r0 + tx] = T[tx][cc];
    }
}

// ---------------------------------------------------------------------------
// v [B*S, :] (row stride ldin, col offset applied by caller) bf16
//   -> vt [(b,h), 128, 2048]. Grid (S/64, VD/64, B*NH), block 256.
// ---------------------------------------------------------------------------
__global__ __launch_bounds__(256) void transpose_v(const u16* __restrict__ in, int ldin,
                                                   u16* __restrict__ out) {
    __shared__ u16 T[64][65];
    const int s0 = blockIdx.x * 64, d0 = blockIdx.y * 64;
    const int bh = blockIdx.z, b = bh >> 5, h = bh & 31;
    const int tx = threadIdx.x & 63, ty = threadIdx.x >> 6;
#pragma unroll
    for (int p = 0; p < 16; ++p) {
        int ss = p * 4 + ty;
        T[ss][tx] = in[(size_t)(b * SS + s0 + ss) * ldin + h * 128 + d0 + tx];
    }
    __syncthreads();
#pragma unroll
    for (int p = 0; p < 16; ++p) {
        int dd = p * 4 + ty;
        out[((size_t)bh * 128 + d0 + dd) * SS + s0 + tx] = T[tx][dd];
    }
}

// ---------------------------------------------------------------------------
// bf16 MFMA GEMM: C[M,N] = A[M,K](lda) @ Bt[N,K](ldb)^T.
// 256x256 tile, BK=32, 8 waves (2M x 4N), 4-slot rolling LDS pipeline:
//   iter kt: barrier(a) -> issue tile kt+3 (4 x global_load_lds, linear dest,
//   pre-swizzled source) -> s_waitcnt vmcnt(12) (tile kt landed; loads span
//   3 tiles of compute) -> barrier(b) -> 12 ds_read_b128 + 32 MFMA.
// No vmcnt(0) drain in the main loop. LDS chunk swizzle: c ^= (row>>1)&3
// (involution; 2-way bank aliasing = free). sched_barrier(0) fences pin the
// GLD16 issue order around the counted waitcnt (compiler may not migrate
// builtins across inline asm otherwise).
// MODE 0: fp32 Cf(ldf). MODE 1: bf16 Cb(ldc).
// MODE 3: bf16 Cb(ldc) full + fp32 Cf(ldf) for cols >= nsplit (col-nsplit).
// ---------------------------------------------------------------------------
template <int MODE>
__global__ __launch_bounds__(512) void gemm_bt(const u16* __restrict__ A, int lda,
                                               const u16* __restrict__ Bt, int ldb,
                                               float* __restrict__ Cf, int ldf,
                                               u16* __restrict__ Cb, int ldc,
                                               int M, int N, int K, int nsplit) {
    __shared__ __align__(16) u16 As[4][256 * 32];   // 64 KiB
    __shared__ __align__(16) u16 Bs[4][256 * 32];   // 64 KiB

    const int tid = threadIdx.x;
    const int bm0 = blockIdx.y * 256, bn0 = blockIdx.x * 256;
    const int w = tid >> 6, lane = tid & 63;
    const int lo = lane & 15, quad = lane >> 4;
    const int wm = (w >> 2) * 128, wn = (w & 3) * 64;  // per-wave 128x64 output

    floatx4 acc[8][4];
#pragma unroll
    for (int m = 0; m < 8; ++m)
#pragma unroll
        for (int n = 0; n < 4; ++n) acc[m][n] = (floatx4){0.f, 0.f, 0.f, 0.f};

    // staging: per matrix per tile, thread covers o = tid*16 + p*8192 bytes.
    // LDS dest linear (o); global source column chunk pre-swizzled with the
    // same involution the reader applies: c ^ ((row>>1)&3).
    int row_[2], gco[2], ldso[2];
#pragma unroll
    for (int p = 0; p < 2; ++p) {
        int o = tid * 16 + p * 8192;
        row_[p] = o >> 6;                       // 64 B per row (32 bf16)
        int c = (o & 63) >> 4;                  // 16B chunk 0..3
        gco[p] = ((c ^ ((row_[p] >> 1) & 3)) << 3);  // u16 col offset in BK
        ldso[p] = o >> 1;                       // u16 linear LDS index
    }

    const u16* Ab = A + (size_t)bm0 * lda;
    const u16* Bb = Bt + (size_t)bn0 * ldb;
    const int NT = K >> 5;

    auto STAGE = [&](int t) {
        const int s = t & 3;
        const int k0 = t << 5;
#pragma unroll
        for (int p = 0; p < 2; ++p)
            GLD16(Ab + (size_t)row_[p] * lda + k0 + gco[p], &As[s][ldso[p]]);
#pragma unroll
        for (int p = 0; p < 2; ++p)
            GLD16(Bb + (size_t)row_[p] * ldb + k0 + gco[p], &Bs[s][ldso[p]]);
    };

    // prologue: fill the pipeline 3 tiles deep
    STAGE(0);
    if (NT > 1) STAGE(1);
    if (NT > 2) STAGE(2);

    for (int kt = 0; kt < NT; ++kt) {
        __builtin_amdgcn_s_barrier();   // (a) all waves done reading slot (kt+3)&3
        if (kt + 3 < NT) STAGE(kt + 3);
        __builtin_amdgcn_sched_barrier(0);  // pin: STAGE loads issued before the wait
        // counted wait: tile kt's 4 loads are the oldest outstanding
        if (kt < NT - 3)       asm volatile("s_waitcnt vmcnt(12)" ::: "memory");
        else if (kt == NT - 3) asm volatile("s_waitcnt vmcnt(8)" ::: "memory");
        else if (kt == NT - 2) asm volatile("s_waitcnt vmcnt(4)" ::: "memory");
        else                   asm volatile("s_waitcnt vmcnt(0)" ::: "memory");
        __builtin_amdgcn_sched_barrier(0);  // pin: nothing hoists above the wait
        __builtin_amdgcn_s_barrier();   // (b) every wave's tile-kt data is in LDS
        __builtin_amdgcn_sched_barrier(0);  // pin: ds_reads stay below barrier (b)

        const int s = kt & 3;
        short8 af[8], bfr[4];
#pragma unroll
        for (int m = 0; m < 8; ++m) {
            const int r = wm + m * 16 + lo;
            af[m] = *(const short8*)&As[s][r * 32 + ((quad ^ ((r >> 1) & 3)) << 3)];
        }
#pragma unroll
        for (int n = 0; n < 4; ++n) {
            const int r = wn + n * 16 + lo;
            bfr[n] = *(const short8*)&Bs[s][r * 32 + ((quad ^ ((r >> 1) & 3)) << 3)];
        }
        __builtin_amdgcn_s_setprio(1);
#pragma unroll
        for (int m = 0; m < 8; ++m)
#pragma unroll
            for (int n = 0; n < 4; ++n)
                acc[m][n] = __builtin_amdgcn_mfma_f32_16x16x32_bf16(af[m], bfr[n], acc[m][n], 0, 0, 0);
        __builtin_amdgcn_s_setprio(0);
    }

#pragma unroll
    for (int m = 0; m < 8; ++m) {
#pragma unroll
        for (int n = 0; n < 4; ++n) {
            const int row = bm0 + wm + m * 16 + quad * 4;
            const int col = bn0 + wn + n * 16 + lo;
#pragma unroll
            for (int r = 0; r < 4; ++r) {
                float v = acc[m][n][r];
                if (MODE == 0) Cf[(size_t)(row + r) * ldf + col] = v;
                if (MODE == 1) Cb[(size_t)(row + r) * ldc + col] = f2bf(v);
                if (MODE == 3) {
                    Cb[(size_t)(row + r) * ldc + col] = f2bf(v);
                    if (col >= nsplit) Cf[(size_t)(row + r) * ldf + (col - nsplit)] = v;
                }
            }
        }
    }
}

// ---------------------------------------------------------------------------
// MFMA flash attention (causal), Q-tile 128 rows/block (wave owns 32 rows),
// K-tile 64 keys. Single-pass softmax (scores bounded; no max shift),
// l computed via 16 ones-columns appended to V^T (pure MFMA, no shuffles).
// Staging via global_load_lds (linear dest, pre-swizzled source); K(kt+1)
// prefetch under PV, V(kt+1) prefetch under next QK+softmax.
// Grid (64, 16): x=bh (same-bh blocks on same XCD), y=qt reversed.
// ---------------------------------------------------------------------------
__global__ __launch_bounds__(256) void mla_attn_mfma(const u16* __restrict__ qm,
                                                     const u16* __restrict__ km, int ldk,
                                                     const u16* __restrict__ vt,
                                                     u16* __restrict__ ao) {
    __shared__ __align__(16) u16 Ks[64 * 128];        // [key][hd], chunk ^= key&15
    __shared__ __align__(16) u16 Vt[(128 + 16) * 64]; // [vd][key], chunk ^= vd&7; rows 128..143 = 1.0
    __shared__ __align__(16) u16 Ps[128 * 68];        // [q][key], stride 68 (conflict-free)

    const int qt = 15 - blockIdx.y;  // reversed: longest blocks dispatch first
    const int bh = blockIdx.x;
    const int b = bh >> 5, h = bh & 31;
    const int tid = threadIdx.x;
    const int w = tid >> 6, lane = tid & 63;
    const int lo = lane & 15, quad = lane >> 4;
    const int q0 = qt * 128;

    const float SCALE_L2E = 0.08838834764831845f * 1.4426950408889634f;

    // ones rows (vd 128..143) for the l-column trick: 16*64 u16 = 512 u32
    {
        u32* p = (u32*)&Vt[128 * 64];
        for (int i = tid; i < 512; i += 256) p[i] = 0x3F803F80u;
    }

    const u16* kbase = km + (size_t)(b * SS) * ldk + h * 128;
    const u16* vtbase = vt + (size_t)bh * 128 * SS;
    const int nkt = 2 * qt + 2;

    // per-thread staging constants: linear LDS dest (o bytes), pre-swizzled
    // global source offsets (XOR involution == the read-side swizzle)
    int ol_[4], kgo[4], vgo[4];
#pragma unroll
    for (int p = 0; p < 4; ++p) {
        int o = tid * 16 + p * 4096;           // byte offset within 16KB tile
        int key = o >> 8, ch = (o & 255) >> 4; // K row, 16B chunk
        kgo[p] = key * ldk + ((ch ^ (key & 15)) << 3);
        int d = o >> 7, ch2 = (o & 127) >> 4;  // V row, 16B chunk
        vgo[p] = d * SS + ((ch2 ^ (d & 7)) << 3);
        ol_[p] = o >> 1;                       // u16 index (linear LDS)
    }

    // prologue: stage tile 0 (K and V) directly to LDS
#pragma unroll
    for (int p = 0; p < 4; ++p) GLD16(kbase + kgo[p], &Ks[ol_[p]]);
#pragma unroll
    for (int p = 0; p < 4; ++p) GLD16(vtbase + vgo[p], &Vt[ol_[p]]);

    // Q fragments: wave w owns q rows w*32 + mf*16 + lo
    short8 qf[2][4];
#pragma unroll
    for (int mf = 0; mf < 2; ++mf) {
        const u16* qrow = qm + (size_t)(b * SS + q0 + w * 32 + mf * 16 + lo) * HH + h * 128;
#pragma unroll
        for (int ks = 0; ks < 4; ++ks) qf[mf][ks] = *(const short8*)(qrow + ks * 32 + quad * 8);
    }

    floatx4 oacc[2][8], olv[2];
#pragma unroll
    for (int mf = 0; mf < 2; ++mf) {
        olv[mf] = (floatx4){0.f, 0.f, 0.f, 0.f};
#pragma unroll
        for (int n = 0; n < 8; ++n) oacc[mf][n] = (floatx4){0.f, 0.f, 0.f, 0.f};
    }

    __syncthreads();  // tile 0 staged (embedded vmcnt(0) drains the GLDs)

    for (int kt = 0; kt < nkt; ++kt) {
        const bool need_mask = (kt >= nkt - 2);
        const bool notlast = (kt + 1 < nkt);

        // ---- QK^T + softmax -> Ps (reads Ks only) ----
#pragma unroll
        for (int mf = 0; mf < 2; ++mf) {
            floatx4 s[4];
#pragma unroll
            for (int nf = 0; nf < 4; ++nf) s[nf] = (floatx4){0.f, 0.f, 0.f, 0.f};
            __builtin_amdgcn_s_setprio(1);
#pragma unroll
            for (int nf = 0; nf < 4; ++nf)
#pragma unroll
                for (int ks = 0; ks < 4; ++ks) {
                    short8 kf = *(const short8*)&Ks[(nf * 16 + lo) * 128 + (((ks * 4 + quad) ^ lo) << 3)];
                    s[nf] = __builtin_amdgcn_mfma_f32_16x16x32_bf16(qf[mf][ks], kf, s[nf], 0, 0, 0);
                }
            __builtin_amdgcn_s_setprio(0);
            // P = exp2(s*scale) (bounded scores: no max shift), masked -> 0
#pragma unroll
            for (int nf = 0; nf < 4; ++nf)
#pragma unroll
                for (int r = 0; r < 4; ++r) {
                    float p = fast_exp2(s[nf][r] * SCALE_L2E);
                    if (need_mask) {
                        int kgi = kt * 64 + nf * 16 + lo;
                        int qg = q0 + w * 32 + mf * 16 + quad * 4 + r;
                        p = (kgi <= qg) ? p : 0.f;
                    }
                    Ps[(w * 32 + mf * 16 + quad * 4 + r) * 68 + nf * 16 + lo] = f2bf(p);
                }
        }

        __syncthreads();  // all waves done reading Ks; drains V(kt) prefetch too

        // prefetch K(kt+1) into Ks — lands under the PV phase below
        if (notlast) {
            const u16* kn = kbase + (size_t)(kt + 1) * 64 * ldk;
#pragma unroll
            for (int p = 0; p < 4; ++p) GLD16(kn + kgo[p], &Ks[ol_[p]]);
        }

        // ---- PV + l (reads Vt + own Ps rows; same-wave Ps dep only) ----
#pragma unroll
        for (int mf = 0; mf < 2; ++mf) {
            short8 pa[2];
#pragma unroll
            for (int ks2 = 0; ks2 < 2; ++ks2)
                pa[ks2] = *(const short8*)&Ps[(w * 32 + mf * 16 + lo) * 68 + ks2 * 32 + quad * 8];
            __builtin_amdgcn_s_setprio(1);
#pragma unroll
            for (int n = 0; n < 8; ++n)
#pragma unroll
                for (int ks2 = 0; ks2 < 2; ++ks2) {
                    short8 vf = *(const short8*)&Vt[(n * 16 + lo) * 64 + (((ks2 * 4 + quad) ^ (lo & 7)) << 3)];
                    oacc[mf][n] = __builtin_amdgcn_mfma_f32_16x16x32_bf16(pa[ks2], vf, oacc[mf][n], 0, 0, 0);
                }
#pragma unroll
            for (int ks2 = 0; ks2 < 2; ++ks2) {
                short8 vf = *(const short8*)&Vt[(128 + lo) * 64 + (((ks2 * 4 + quad) ^ (lo & 7)) << 3)];
                olv[mf] = __builtin_amdgcn_mfma_f32_16x16x32_bf16(pa[ks2], vf, olv[mf], 0, 0, 0);
            }
            __builtin_amdgcn_s_setprio(0);
        }

        __syncthreads();  // all waves done reading Vt; drains K(kt+1) prefetch

        // prefetch V(kt+1) into Vt — lands under the next QK+softmax phase
        if (notlast) {
            const u16* vn = vtbase + (size_t)(kt + 1) * 64;
#pragma unroll
            for (int p = 0; p < 4; ++p) GLD16(vn + vgo[p], &Vt[ol_[p]]);
        }
    }

    // epilogue: O / l
#pragma unroll
    for (int mf = 0; mf < 2; ++mf) {
        u16* obase = ao + (size_t)(b * SS + q0 + w * 32 + mf * 16 + quad * 4) * HH + h * 128;
#pragma unroll
        for (int r = 0; r < 4; ++r) {
            float inv = 1.f / olv[mf][r];
#pragma unroll
            for (int n = 0; n < 8; ++n)
                obase[(size_t)r * HH + n * 16 + lo] = f2bf(oacc[mf][n][r] * inv);
        }
    }
}

// ---------------------------------------------------------------------------
// Orchestration. ws layout (u16 elements):
//   hs_bf @0 (16.8M)            -> vt aliases after GF1
//   q_bf @16777216 (16.8M)
//   kv_bf @33554432 (33.55M)    [4096][8192]: k cols 0..4095, v cols 4096..8191
//   ao_bf @67108864 (16.8M)
//   wqa_kvaT @83886080 (8.39M)  [2048][4096]: w_qaT rows 0..1535, w_kvaT rows 1536..2047
//   w_qbT @92274688 (6.29M)
//   wkv_bT @98566144 (4.19M)    [8192][512]: w_kbT rows 0..4095, w_vbT rows 4096..8191
//   w_oT @102760448 (16.8M)
//   qc_ckv @119537664 (8.39M)   [4096][2048]: q_c cols 0..1535, ckv cols 1536..2047
// Total 255.9 MB.
// ---------------------------------------------------------------------------
extern "C" void kernel_launch(void* const* d_in, const int* in_sizes, int n_in,
                              void* d_out, int out_size, void* d_ws, size_t ws_size,
                              hipStream_t stream) {
    const float* hs    = (const float*)d_in[0];
    const float* w_qa  = (const float*)d_in[1];
    const float* w_qb  = (const float*)d_in[2];
    const float* w_kva = (const float*)d_in[3];
    const float* w_kb  = (const float*)d_in[4];
    const float* w_vb  = (const float*)d_in[5];
    const float* w_o   = (const float*)d_in[6];

    float* out   = (float*)d_out;
    float* ckv_f = out + (size_t)MROWS * HH;

    u16* ws = (u16*)d_ws;
    u16* hs_bf    = ws;
    u16* vt       = ws;                       // aliases hs_bf (dead after GF1)
    u16* q_bf     = ws + 16777216ull;
    u16* kv_bf    = ws + 33554432ull;         // [4096][8192]
    u16* ao_bf    = ws + 67108864ull;
    u16* wqa_kvaT = ws + 83886080ull;         // [2048][4096]
    u16* w_qbT    = ws + 92274688ull;
    u16* wkv_bT   = ws + 98566144ull;         // [8192][512]
    u16* w_oT     = ws + 102760448ull;
    u16* qc_ckv   = ws + 119537664ull;        // [4096][2048]

    dim3 blk(256);
    dim3 blkg(512);

    cvt_bf16<<<2048, blk, 0, stream>>>(hs, hs_bf, (MROWS * HH) / 4);
    transpose_cvt<<<dim3(QRANK / 64, HH / 64), blk, 0, stream>>>(w_qa, wqa_kvaT, HH, QRANK);
    transpose_cvt<<<dim3(KVRANK / 64, HH / 64), blk, 0, stream>>>(w_kva, wqa_kvaT + 1536ull * 4096, HH, KVRANK);
    transpose_cvt<<<dim3(HH / 64, QRANK / 64), blk, 0, stream>>>(w_qb, w_qbT, QRANK, HH);
    transpose_cvt<<<dim3(HH / 64, KVRANK / 64), blk, 0, stream>>>(w_kb, wkv_bT, KVRANK, HH);
    transpose_cvt<<<dim3(HH / 64, KVRANK / 64), blk, 0, stream>>>(w_vb, wkv_bT + 4096ull * 512, KVRANK, HH);
    transpose_cvt<<<dim3(HH / 64, HH / 64), blk, 0, stream>>>(w_o, w_oT, HH, HH);

    // GF1: [q_c | ckv] = hs @ [w_qa | w_kva]   (N=2048, K=4096); ckv also fp32->d_out
    gemm_bt<3><<<dim3(2048 / 256, MROWS / 256), blkg, 0, stream>>>(
        hs_bf, HH, wqa_kvaT, HH, ckv_f, KVRANK, qc_ckv, 2048, MROWS, 2048, HH, QRANK);
    // G2: q = q_c @ w_qb   (K=1536, A lda=2048)
    gemm_bt<1><<<dim3(HH / 256, MROWS / 256), blkg, 0, stream>>>(
        qc_ckv, 2048, w_qbT, QRANK, nullptr, 0, q_bf, HH, MROWS, HH, QRANK, 0);
    // GKV: [k | v] = ckv @ [w_kb | w_vb]   (N=8192, K=512, A lda=2048)
    gemm_bt<1><<<dim3(8192 / 256, MROWS / 256), blkg, 0, stream>>>(
        qc_ckv + 1536, 2048, wkv_bT, KVRANK, nullptr, 0, kv_bf, 8192, MROWS, 8192, KVRANK, 0);
    // V^T per head (vt aliases dead hs_bf)
    transpose_v<<<dim3(SS / 64, VDIM / 64, BB * NHEADS), blk, 0, stream>>>(kv_bf + 4096, 8192, vt);
    // causal MFMA attention: grid (bh, qt) — longest-first, same-bh on same XCD
    mla_attn_mfma<<<dim3(BB * NHEADS, 16), blk, 0, stream>>>(q_bf, kv_bf, 8192, vt, ao_bf);
    // G7: out = ao @ w_o
    gemm_bt<0><<<dim3(HH / 256, MROWS / 256), blkg, 0, stream>>>(
        ao_bf, HH, w_oT, HH, out, HH, nullptr, 0, MROWS, HH, HH, 0);
}

// Round 4
// 788.122 us; speedup vs baseline: 1.2742x; 1.0141x over previous
//
#include <hip/hip_runtime.h>
#include <hip/hip_bf16.h>
#include <math.h>

// MLA attention forward, bf16 MFMA (round 7: GEMM K-loop restructured into the
// 4-phase-per-K-tile fine interleave (m196/m218/m201 lineage): per phase
// {ds_read subtile || stage 1 half-tile -> vmcnt(10)+barrier -> 16-MFMA cluster},
// 2-slot double-buffered LDS, region-ledgered staging. Attention unchanged.
#define BB 2
#define SS 2048
#define HH 4096
#define NHEADS 32
#define HDIM 128
#define VDIM 128
#define QRANK 1536
#define KVRANK 512
#define MROWS (BB * SS) /* 4096 */

typedef unsigned short u16;
typedef unsigned int u32;
typedef short short8 __attribute__((ext_vector_type(8)));   // 8 bf16 (4 VGPRs)
typedef float floatx4 __attribute__((ext_vector_type(4)));

#if __has_builtin(__builtin_amdgcn_exp2f)
__device__ __forceinline__ float fast_exp2(float x) { return __builtin_amdgcn_exp2f(x); }
#else
__device__ __forceinline__ float fast_exp2(float x) { return exp2f(x); }
#endif

// fp32 -> bf16 (RNE)
__device__ __forceinline__ u16 f2bf(float f) {
    u32 u = __float_as_uint(f);
    u += 0x7fffu + ((u >> 16) & 1u);
    return (u16)(u >> 16);
}

// async global->LDS, 16 bytes per lane
#define GLD16(gp, lp)                                                        \
    __builtin_amdgcn_global_load_lds(                                        \
        (const __attribute__((address_space(1))) void*)(gp),                 \
        (__attribute__((address_space(3))) void*)(lp), 16, 0, 0)

// ---------------------------------------------------------------------------
// fp32 -> bf16 convert
// ---------------------------------------------------------------------------
__global__ __launch_bounds__(256) void cvt_bf16(const float* __restrict__ in,
                                                u16* __restrict__ out, int n4) {
    int idx = blockIdx.x * 256 + threadIdx.x;
    int stride = gridDim.x * 256;
    for (int i = idx; i < n4; i += stride) {
        float4 f = ((const float4*)in)[i];
        u32 lo = (u32)f2bf(f.x) | ((u32)f2bf(f.y) << 16);
        u32 hi = (u32)f2bf(f.z) | ((u32)f2bf(f.w) << 16);
        ((uint2*)out)[i] = make_uint2(lo, hi);
    }
}

// ---------------------------------------------------------------------------
// fp32 [R,C] -> bf16 [C,R] transpose+convert. Grid (C/64, R/64), block 256.
// ---------------------------------------------------------------------------
__global__ __launch_bounds__(256) void transpose_cvt(const float* __restrict__ in,
                                                     u16* __restrict__ out,
                                                     int R, int C) {
    __shared__ u16 T[64][65];
    const int c0 = blockIdx.x * 64, r0 = blockIdx.y * 64;
    const int tx = threadIdx.x & 63, ty = threadIdx.x >> 6;
#pragma unroll
    for (int p = 0; p < 16; ++p) {
        int rr = p * 4 + ty;
        T[rr][tx] = f2bf(in[(size_t)(r0 + rr) * C + c0 + tx]);
    }
    __syncthreads();
#pragma unroll
    for (int p = 0; p < 16; ++p) {
        int cc = p * 4 + ty;
        out[(size_t)(c0 + cc) * R + r0 + tx] = T[tx][cc];
    }
}

// ---------------------------------------------------------------------------
// v [B*S, :] (row stride ldin, col offset applied by caller) bf16
//   -> vt [(b,h), 128, 2048]. Grid (S/64, VD/64, B*NH), block 256.
// ---------------------------------------------------------------------------
__global__ __launch_bounds__(256) void transpose_v(const u16* __restrict__ in, int ldin,
                                                   u16* __restrict__ out) {
    __shared__ u16 T[64][65];
    const int s0 = blockIdx.x * 64, d0 = blockIdx.y * 64;
    const int bh = blockIdx.z, b = bh >> 5, h = bh & 31;
    const int tx = threadIdx.x & 63, ty = threadIdx.x >> 6;
#pragma unroll
    for (int p = 0; p < 16; ++p) {
        int ss = p * 4 + ty;
        T[ss][tx] = in[(size_t)(b * SS + s0 + ss) * ldin + h * 128 + d0 + tx];
    }
    __syncthreads();
#pragma unroll
    for (int p = 0; p < 16; ++p) {
        int dd = p * 4 + ty;
        out[((size_t)bh * 128 + d0 + dd) * SS + s0 + tx] = T[tx][dd];
    }
}

// ---------------------------------------------------------------------------
// bf16 MFMA GEMM: C[M,N] = A[M,K](lda) @ Bt[N,K](ldb)^T.
// 256x256 tile, BK=64, 8 waves (2M x 4N, per-wave 128x64 out), 2-slot dbuf LDS.
// 4 phases per K-tile; per phase: {ds_read subtile || stage 1 half-tile (2 x
// global_load_lds, linear dest, pre-swizzled source) -> s_waitcnt vmcnt(10) +
// s_barrier -> 16-MFMA cluster}. Region ledger:
//   A-part1 = rows {0-63,128-191} (read P1), A-part2 = rows {64-127,192-255} (P3)
//   B-part1 = rows {0-31,64-95,128-159,192-223} (P1), B-part2 = rest (P2)
//   stage: P1 -> A2(t+1) [freed (t-1).P3]; P2 -> A1(t+2) [freed t.P1, behind
//   P1's lgkmcnt(0)+barrier]; P3 -> B1(t+2) [freed t.P1]; P4 -> B2(t+2) [freed t.P2].
//   every read's data staged >=5 phases back => vmcnt(10) at each barrier
//   publishes it (2 loads/phase). Tail (t>=NT-2): vmcnt(0).
// LDS swizzle: 16B chunk c ^= (row&7) (involution, both sides) -> <=2-way = free.
// MODE 0: fp32 Cf(ldf). MODE 1: bf16 Cb(ldc).
// MODE 3: bf16 Cb(ldc) full + fp32 Cf(ldf) for cols >= nsplit (col-nsplit).
// ---------------------------------------------------------------------------
#define PHASE_BAR(NLIT)                                                          \
    __builtin_amdgcn_sched_barrier(0);                                           \
    asm volatile("s_waitcnt vmcnt(" NLIT ")\n\ts_barrier" ::: "memory");         \
    __builtin_amdgcn_sched_barrier(0)

#define MFMA_Q(AH, BH, AFR, BFR)                                                 \
    __builtin_amdgcn_s_setprio(1);                                               \
    _Pragma("unroll") for (int m_ = 0; m_ < 4; ++m_)                             \
    _Pragma("unroll") for (int n_ = 0; n_ < 2; ++n_)                             \
    _Pragma("unroll") for (int ks_ = 0; ks_ < 2; ++ks_)                          \
        acc[m_ + (AH)*4][n_ + (BH)*2] = __builtin_amdgcn_mfma_f32_16x16x32_bf16( \
            AFR[m_][ks_], BFR[n_][ks_], acc[m_ + (AH)*4][n_ + (BH)*2], 0, 0, 0); \
    __builtin_amdgcn_s_setprio(0);                                               \
    __builtin_amdgcn_sched_barrier(0)

#define GTILE(T, WL)                                                              \
    {                                                                             \
        const int slot = (T) & 1;                                                 \
        short8 a0[4][2], a1[4][2], b0[2][2], b1[2][2];                            \
        /* ---- P1: read af_lo + bf_lo; stage A2(t+1); MFMA (lo,lo) ---- */       \
        _Pragma("unroll") for (int m_ = 0; m_ < 4; ++m_)                          \
        _Pragma("unroll") for (int ks_ = 0; ks_ < 2; ++ks_)                       \
            a0[m_][ks_] = *(const short8*)&As[slot][(wm + m_ * 16 + lo) * 64 +    \
                                                    (((ks_ * 4 + quad) ^ lo7) << 3)]; \
        _Pragma("unroll") for (int n_ = 0; n_ < 2; ++n_)                          \
        _Pragma("unroll") for (int ks_ = 0; ks_ < 2; ++ks_)                       \
            b0[n_][ks_] = *(const short8*)&Bs[slot][(wn + n_ * 16 + lo) * 64 +    \
                                                    (((ks_ * 4 + quad) ^ lo7) << 3)]; \
        if ((T) > 0 && (T) + 1 < NT) STAGE_A((T) + 1, 1);                         \
        PHASE_BAR(WL);                                                            \
        MFMA_Q(0, 0, a0, b0);                                                     \
        asm volatile("s_waitcnt lgkmcnt(0)\n\ts_barrier" ::: "memory");           \
        __builtin_amdgcn_sched_barrier(0);                                        \
        /* ---- P2: read bf_hi; stage A1(t+2); MFMA (lo,hi) ---- */               \
        _Pragma("unroll") for (int n_ = 0; n_ < 2; ++n_)                          \
        _Pragma("unroll") for (int ks_ = 0; ks_ < 2; ++ks_)                       \
            b1[n_][ks_] = *(const short8*)&Bs[slot][(wn + 32 + n_ * 16 + lo) * 64 + \
                                                    (((ks_ * 4 + quad) ^ lo7) << 3)]; \
        if ((T) + 2 < NT) STAGE_A((T) + 2, 0);                                    \
        PHASE_BAR(WL);                                                            \
        MFMA_Q(0, 1, a0, b1);                                                     \
        /* ---- P3: read af_hi; stage B1(t+2); MFMA (hi,lo) ---- */               \
        _Pragma("unroll") for (int m_ = 0; m_ < 4; ++m_)                          \
        _Pragma("unroll") for (int ks_ = 0; ks_ < 2; ++ks_)                       \
            a1[m_][ks_] = *(const short8*)&As[slot][(wm + 64 + m_ * 16 + lo) * 64 + \
                                                    (((ks_ * 4 + quad) ^ lo7) << 3)]; \
        if ((T) + 2 < NT) STAGE_B((T) + 2, 0);                                    \
        PHASE_BAR(WL);                                                            \
        MFMA_Q(1, 0, a1, b0);                                                     \
        /* ---- P4: stage B2(t+2); MFMA (hi,hi) ---- */                           \
        if ((T) + 2 < NT) STAGE_B((T) + 2, 1);                                    \
        PHASE_BAR(WL);                                                            \
        MFMA_Q(1, 1, a1, b1);                                                     \
    }

template <int MODE>
__global__ __launch_bounds__(512) void gemm_bt(const u16* __restrict__ A, int lda,
                                               const u16* __restrict__ Bt, int ldb,
                                               float* __restrict__ Cf, int ldf,
                                               u16* __restrict__ Cb, int ldc,
                                               int M, int N, int K, int nsplit) {
    __shared__ __align__(16) u16 As[2][256 * 64];   // 64 KiB
    __shared__ __align__(16) u16 Bs[2][256 * 64];   // 64 KiB

    const int tid = threadIdx.x;
    const int bm0 = blockIdx.y * 256, bn0 = blockIdx.x * 256;
    const int w = tid >> 6, lane = tid & 63;
    const int lo = lane & 15, quad = lane >> 4;
    const int lo7 = lane & 7, l8 = lane >> 3;
    const int wm = (w >> 2) * 128, wn = (w & 3) * 64;  // per-wave 128x64 output

    floatx4 acc[8][4];
#pragma unroll
    for (int m = 0; m < 8; ++m)
#pragma unroll
        for (int n = 0; n < 4; ++n) acc[m][n] = (floatx4){0.f, 0.f, 0.f, 0.f};

    const u16* Ab = A + (size_t)bm0 * lda;
    const u16* Bb = Bt + (size_t)bn0 * ldb;
    const int NT = K >> 6;

    // Staging geometry: one GLD16 per wave covers 8 consecutive LDS rows
    // (64 lanes x 16 B = 1 KiB, row = 128 B). idx = w*2+p selects the 8-row
    // group within the part. Source column chunk pre-swizzled: lane writes
    // LDS chunk (l&7) of row (row0 + l>>3); source chunk = (l&7) ^ (l>>3)
    // (row&7 == l>>3 since row0 % 8 == 0) -> reader XOR (r&7) recovers it.
    const u16* aSrc[2][2]; const u16* bSrc[2][2];
    int aDst[2][2], bDst[2][2];
    const int csw = (lo7 ^ l8) << 3;   // u16 offset of swizzled 16B chunk
#pragma unroll
    for (int p = 0; p < 2; ++p) {
        const int idx = w * 2 + p;
#pragma unroll
        for (int P = 0; P < 2; ++P) {
            const int ra = (idx >> 3) * 128 + (idx & 7) * 8 + P * 64;
            aSrc[P][p] = Ab + (size_t)(ra + l8) * lda + csw;
            aDst[P][p] = ra * 64 + lane * 8;
            const int rb = (idx >> 2) * 64 + (idx & 3) * 8 + P * 32;
            bSrc[P][p] = Bb + (size_t)(rb + l8) * ldb + csw;
            bDst[P][p] = rb * 64 + lane * 8;
        }
    }

    auto STAGE_A = [&](int t, int P) {
        const int s = t & 1;
#pragma unroll
        for (int p = 0; p < 2; ++p)
            GLD16(aSrc[P][p] + t * 64, &As[s][aDst[P][p]]);
    };
    auto STAGE_B = [&](int t, int P) {
        const int s = t & 1;
#pragma unroll
        for (int p = 0; p < 2; ++p)
            GLD16(bSrc[P][p] + t * 64, &Bs[s][bDst[P][p]]);
    };

    // prologue: fully stage tiles 0 and 1, drain, publish
    STAGE_A(0, 0); STAGE_A(0, 1); STAGE_B(0, 0); STAGE_B(0, 1);
    if (NT > 1) { STAGE_A(1, 0); STAGE_A(1, 1); STAGE_B(1, 0); STAGE_B(1, 1); }
    asm volatile("s_waitcnt vmcnt(0)" ::: "memory");
    __builtin_amdgcn_s_barrier();
    __builtin_amdgcn_sched_barrier(0);

    int t = 0;
    for (; t + 2 < NT; ++t) GTILE(t, "10");
    for (; t < NT; ++t) GTILE(t, "0");

#pragma unroll
    for (int m = 0; m < 8; ++m) {
#pragma unroll
        for (int n = 0; n < 4; ++n) {
            const int row = bm0 + wm + m * 16 + quad * 4;
            const int col = bn0 + wn + n * 16 + lo;
#pragma unroll
            for (int r = 0; r < 4; ++r) {
                float v = acc[m][n][r];
                if (MODE == 0) Cf[(size_t)(row + r) * ldf + col] = v;
                if (MODE == 1) Cb[(size_t)(row + r) * ldc + col] = f2bf(v);
                if (MODE == 3) {
                    Cb[(size_t)(row + r) * ldc + col] = f2bf(v);
                    if (col >= nsplit) Cf[(size_t)(row + r) * ldf + (col - nsplit)] = v;
                }
            }
        }
    }
}

// ---------------------------------------------------------------------------
// MFMA flash attention (causal), Q-tile 128 rows/block (wave owns 32 rows),
// K-tile 64 keys. Single-pass softmax (scores bounded; no max shift),
// l computed via 16 ones-columns appended to V^T (pure MFMA, no shuffles).
// Staging via global_load_lds (linear dest, pre-swizzled source); K(kt+1)
// prefetch under PV, V(kt+1) prefetch under next QK+softmax.
// Grid (64, 16): x=bh (same-bh blocks on same XCD), y=qt reversed.
// ---------------------------------------------------------------------------
__global__ __launch_bounds__(256) void mla_attn_mfma(const u16* __restrict__ qm,
                                                     const u16* __restrict__ km, int ldk,
                                                     const u16* __restrict__ vt,
                                                     u16* __restrict__ ao) {
    __shared__ __align__(16) u16 Ks[64 * 128];        // [key][hd], chunk ^= key&15
    __shared__ __align__(16) u16 Vt[(128 + 16) * 64]; // [vd][key], chunk ^= vd&7; rows 128..143 = 1.0
    __shared__ __align__(16) u16 Ps[128 * 68];        // [q][key], stride 68 (conflict-free)

    const int qt = 15 - blockIdx.y;  // reversed: longest blocks dispatch first
    const int bh = blockIdx.x;
    const int b = bh >> 5, h = bh & 31;
    const int tid = threadIdx.x;
    const int w = tid >> 6, lane = tid & 63;
    const int lo = lane & 15, quad = lane >> 4;
    const int q0 = qt * 128;

    const float SCALE_L2E = 0.08838834764831845f * 1.4426950408889634f;

    // ones rows (vd 128..143) for the l-column trick: 16*64 u16 = 512 u32
    {
        u32* p = (u32*)&Vt[128 * 64];
        for (int i = tid; i < 512; i += 256) p[i] = 0x3F803F80u;
    }

    const u16* kbase = km + (size_t)(b * SS) * ldk + h * 128;
    const u16* vtbase = vt + (size_t)bh * 128 * SS;
    const int nkt = 2 * qt + 2;

    // per-thread staging constants: linear LDS dest (o bytes), pre-swizzled
    // global source offsets (XOR involution == the read-side swizzle)
    int ol_[4], kgo[4], vgo[4];
#pragma unroll
    for (int p = 0; p < 4; ++p) {
        int o = tid * 16 + p * 4096;           // byte offset within 16KB tile
        int key = o >> 8, ch = (o & 255) >> 4; // K row, 16B chunk
        kgo[p] = key * ldk + ((ch ^ (key & 15)) << 3);
        int d = o >> 7, ch2 = (o & 127) >> 4;  // V row, 16B chunk
        vgo[p] = d * SS + ((ch2 ^ (d & 7)) << 3);
        ol_[p] = o >> 1;                       // u16 index (linear LDS)
    }

    // prologue: stage tile 0 (K and V) directly to LDS
#pragma unroll
    for (int p = 0; p < 4; ++p) GLD16(kbase + kgo[p], &Ks[ol_[p]]);
#pragma unroll
    for (int p = 0; p < 4; ++p) GLD16(vtbase + vgo[p], &Vt[ol_[p]]);

    // Q fragments: wave w owns q rows w*32 + mf*16 + lo
    short8 qf[2][4];
#pragma unroll
    for (int mf = 0; mf < 2; ++mf) {
        const u16* qrow = qm + (size_t)(b * SS + q0 + w * 32 + mf * 16 + lo) * HH + h * 128;
#pragma unroll
        for (int ks = 0; ks < 4; ++ks) qf[mf][ks] = *(const short8*)(qrow + ks * 32 + quad * 8);
    }

    floatx4 oacc[2][8], olv[2];
#pragma unroll
    for (int mf = 0; mf < 2; ++mf) {
        olv[mf] = (floatx4){0.f, 0.f, 0.f, 0.f};
#pragma unroll
        for (int n = 0; n < 8; ++n) oacc[mf][n] = (floatx4){0.f, 0.f, 0.f, 0.f};
    }

    __syncthreads();  // tile 0 staged (embedded vmcnt(0) drains the GLDs)

    for (int kt = 0; kt < nkt; ++kt) {
        const bool need_mask = (kt >= nkt - 2);
        const bool notlast = (kt + 1 < nkt);

        // ---- QK^T + softmax -> Ps (reads Ks only) ----
#pragma unroll
        for (int mf = 0; mf < 2; ++mf) {
            floatx4 s[4];
#pragma unroll
            for (int nf = 0; nf < 4; ++nf) s[nf] = (floatx4){0.f, 0.f, 0.f, 0.f};
            __builtin_amdgcn_s_setprio(1);
#pragma unroll
            for (int nf = 0; nf < 4; ++nf)
#pragma unroll
                for (int ks = 0; ks < 4; ++ks) {
                    short8 kf = *(const short8*)&Ks[(nf * 16 + lo) * 128 + (((ks * 4 + quad) ^ lo) << 3)];
                    s[nf] = __builtin_amdgcn_mfma_f32_16x16x32_bf16(qf[mf][ks], kf, s[nf], 0, 0, 0);
                }
            __builtin_amdgcn_s_setprio(0);
            // P = exp2(s*scale) (bounded scores: no max shift), masked -> 0
#pragma unroll
            for (int nf = 0; nf < 4; ++nf)
#pragma unroll
                for (int r = 0; r < 4; ++r) {
                    float p = fast_exp2(s[nf][r] * SCALE_L2E);
                    if (need_mask) {
                        int kgi = kt * 64 + nf * 16 + lo;
                        int qg = q0 + w * 32 + mf * 16 + quad * 4 + r;
                        p = (kgi <= qg) ? p : 0.f;
                    }
                    Ps[(w * 32 + mf * 16 + quad * 4 + r) * 68 + nf * 16 + lo] = f2bf(p);
                }
        }

        __syncthreads();  // all waves done reading Ks; drains V(kt) prefetch too

        // prefetch K(kt+1) into Ks — lands under the PV phase below
        if (notlast) {
            const u16* kn = kbase + (size_t)(kt + 1) * 64 * ldk;
#pragma unroll
            for (int p = 0; p < 4; ++p) GLD16(kn + kgo[p], &Ks[ol_[p]]);
        }

        // ---- PV + l (reads Vt + own Ps rows; same-wave Ps dep only) ----
#pragma unroll
        for (int mf = 0; mf < 2; ++mf) {
            short8 pa[2];
#pragma unroll
            for (int ks2 = 0; ks2 < 2; ++ks2)
                pa[ks2] = *(const short8*)&Ps[(w * 32 + mf * 16 + lo) * 68 + ks2 * 32 + quad * 8];
            __builtin_amdgcn_s_setprio(1);
#pragma unroll
            for (int n = 0; n < 8; ++n)
#pragma unroll
                for (int ks2 = 0; ks2 < 2; ++ks2) {
                    short8 vf = *(const short8*)&Vt[(n * 16 + lo) * 64 + (((ks2 * 4 + quad) ^ (lo & 7)) << 3)];
                    oacc[mf][n] = __builtin_amdgcn_mfma_f32_16x16x32_bf16(pa[ks2], vf, oacc[mf][n], 0, 0, 0);
                }
#pragma unroll
            for (int ks2 = 0; ks2 < 2; ++ks2) {
                short8 vf = *(const short8*)&Vt[(128 + lo) * 64 + (((ks2 * 4 + quad) ^ (lo & 7)) << 3)];
                olv[mf] = __builtin_amdgcn_mfma_f32_16x16x32_bf16(pa[ks2], vf, olv[mf], 0, 0, 0);
            }
            __builtin_amdgcn_s_setprio(0);
        }

        __syncthreads();  // all waves done reading Vt; drains K(kt+1) prefetch

        // prefetch V(kt+1) into Vt — lands under the next QK+softmax phase
        if (notlast) {
            const u16* vn = vtbase + (size_t)(kt + 1) * 64;
#pragma unroll
            for (int p = 0; p < 4; ++p) GLD16(vn + vgo[p], &Vt[ol_[p]]);
        }
    }

    // epilogue: O / l
#pragma unroll
    for (int mf = 0; mf < 2; ++mf) {
        u16* obase = ao + (size_t)(b * SS + q0 + w * 32 + mf * 16 + quad * 4) * HH + h * 128;
#pragma unroll
        for (int r = 0; r < 4; ++r) {
            float inv = 1.f / olv[mf][r];
#pragma unroll
            for (int n = 0; n < 8; ++n)
                obase[(size_t)r * HH + n * 16 + lo] = f2bf(oacc[mf][n][r] * inv);
        }
    }
}

// ---------------------------------------------------------------------------
// Orchestration. ws layout (u16 elements):
//   hs_bf @0 (16.8M)            -> vt aliases after GF1
//   q_bf @16777216 (16.8M)
//   kv_bf @33554432 (33.55M)    [4096][8192]: k cols 0..4095, v cols 4096..8191
//   ao_bf @67108864 (16.8M)
//   wqa_kvaT @83886080 (8.39M)  [2048][4096]: w_qaT rows 0..1535, w_kvaT rows 1536..2047
//   w_qbT @92274688 (6.29M)
//   wkv_bT @98566144 (4.19M)    [8192][512]: w_kbT rows 0..4095, w_vbT rows 4096..8191
//   w_oT @102760448 (16.8M)
//   qc_ckv @119537664 (8.39M)   [4096][2048]: q_c cols 0..1535, ckv cols 1536..2047
// Total 255.9 MB.
// ---------------------------------------------------------------------------
extern "C" void kernel_launch(void* const* d_in, const int* in_sizes, int n_in,
                              void* d_out, int out_size, void* d_ws, size_t ws_size,
                              hipStream_t stream) {
    const float* hs    = (const float*)d_in[0];
    const float* w_qa  = (const float*)d_in[1];
    const float* w_qb  = (const float*)d_in[2];
    const float* w_kva = (const float*)d_in[3];
    const float* w_kb  = (const float*)d_in[4];
    const float* w_vb  = (const float*)d_in[5];
    const float* w_o   = (const float*)d_in[6];

    float* out   = (float*)d_out;
    float* ckv_f = out + (size_t)MROWS * HH;

    u16* ws = (u16*)d_ws;
    u16* hs_bf    = ws;
    u16* vt       = ws;                       // aliases hs_bf (dead after GF1)
    u16* q_bf     = ws + 16777216ull;
    u16* kv_bf    = ws + 33554432ull;         // [4096][8192]
    u16* ao_bf    = ws + 67108864ull;
    u16* wqa_kvaT = ws + 83886080ull;         // [2048][4096]
    u16* w_qbT    = ws + 92274688ull;
    u16* wkv_bT   = ws + 98566144ull;         // [8192][512]
    u16* w_oT     = ws + 102760448ull;
    u16* qc_ckv   = ws + 119537664ull;        // [4096][2048]

    dim3 blk(256);
    dim3 blkg(512);

    cvt_bf16<<<2048, blk, 0, stream>>>(hs, hs_bf, (MROWS * HH) / 4);
    transpose_cvt<<<dim3(QRANK / 64, HH / 64), blk, 0, stream>>>(w_qa, wqa_kvaT, HH, QRANK);
    transpose_cvt<<<dim3(KVRANK / 64, HH / 64), blk, 0, stream>>>(w_kva, wqa_kvaT + 1536ull * 4096, HH, KVRANK);
    transpose_cvt<<<dim3(HH / 64, QRANK / 64), blk, 0, stream>>>(w_qb, w_qbT, QRANK, HH);
    transpose_cvt<<<dim3(HH / 64, KVRANK / 64), blk, 0, stream>>>(w_kb, wkv_bT, KVRANK, HH);
    transpose_cvt<<<dim3(HH / 64, KVRANK / 64), blk, 0, stream>>>(w_vb, wkv_bT + 4096ull * 512, KVRANK, HH);
    transpose_cvt<<<dim3(HH / 64, HH / 64), blk, 0, stream>>>(w_o, w_oT, HH, HH);

    // GF1: [q_c | ckv] = hs @ [w_qa | w_kva]   (N=2048, K=4096); ckv also fp32->d_out
    gemm_bt<3><<<dim3(2048 / 256, MROWS / 256), blkg, 0, stream>>>(
        hs_bf, HH, wqa_kvaT, HH, ckv_f, KVRANK, qc_ckv, 2048, MROWS, 2048, HH, QRANK);
    // G2: q = q_c @ w_qb   (K=1536, A lda=2048)
    gemm_bt<1><<<dim3(HH / 256, MROWS / 256), blkg, 0, stream>>>(
        qc_ckv, 2048, w_qbT, QRANK, nullptr, 0, q_bf, HH, MROWS, HH, QRANK, 0);
    // GKV: [k | v] = ckv @ [w_kb | w_vb]   (N=8192, K=512, A lda=2048)
    gemm_bt<1><<<dim3(8192 / 256, MROWS / 256), blkg, 0, stream>>>(
        qc_ckv + 1536, 2048, wkv_bT, KVRANK, nullptr, 0, kv_bf, 8192, MROWS, 8192, KVRANK, 0);
    // V^T per head (vt aliases dead hs_bf)
    transpose_v<<<dim3(SS / 64, VDIM / 64, BB * NHEADS), blk, 0, stream>>>(kv_bf + 4096, 8192, vt);
    // causal MFMA attention: grid (bh, qt) — longest-first, same-bh on same XCD
    mla_attn_mfma<<<dim3(BB * NHEADS, 16), blk, 0, stream>>>(q_bf, kv_bf, 8192, vt, ao_bf);
    // G7: out = ao @ w_o
    gemm_bt<0><<<dim3(HH / 256, MROWS / 256), blkg, 0, stream>>>(
        ao_bf, HH, w_oT, HH, out, HH, nullptr, 0, MROWS, HH, HH, 0);
}

// Round 5
// 693.403 us; speedup vs baseline: 1.4483x; 1.1366x over previous
//
#include <hip/hip_runtime.h>
#include <hip/hip_bf16.h>
#include <math.h>

// MLA attention forward, bf16 MFMA (round 8: faithful m201-style 8-phase GEMM —
// double barrier per phase, region-ledgered in-slot staging, vmcnt(6) at exactly
// phases 4 and 8, one sched_barrier per phase. Attention unchanged.
#define BB 2
#define SS 2048
#define HH 4096
#define NHEADS 32
#define HDIM 128
#define VDIM 128
#define QRANK 1536
#define KVRANK 512
#define MROWS (BB * SS) /* 4096 */

typedef unsigned short u16;
typedef unsigned int u32;
typedef short short8 __attribute__((ext_vector_type(8)));   // 8 bf16 (4 VGPRs)
typedef float floatx4 __attribute__((ext_vector_type(4)));

#if __has_builtin(__builtin_amdgcn_exp2f)
__device__ __forceinline__ float fast_exp2(float x) { return __builtin_amdgcn_exp2f(x); }
#else
__device__ __forceinline__ float fast_exp2(float x) { return exp2f(x); }
#endif

// fp32 -> bf16 (RNE)
__device__ __forceinline__ u16 f2bf(float f) {
    u32 u = __float_as_uint(f);
    u += 0x7fffu + ((u >> 16) & 1u);
    return (u16)(u >> 16);
}

// async global->LDS, 16 bytes per lane
#define GLD16(gp, lp)                                                        \
    __builtin_amdgcn_global_load_lds(                                        \
        (const __attribute__((address_space(1))) void*)(gp),                 \
        (__attribute__((address_space(3))) void*)(lp), 16, 0, 0)

// ---------------------------------------------------------------------------
// fp32 -> bf16 convert
// ---------------------------------------------------------------------------
__global__ __launch_bounds__(256) void cvt_bf16(const float* __restrict__ in,
                                                u16* __restrict__ out, int n4) {
    int idx = blockIdx.x * 256 + threadIdx.x;
    int stride = gridDim.x * 256;
    for (int i = idx; i < n4; i += stride) {
        float4 f = ((const float4*)in)[i];
        u32 lo = (u32)f2bf(f.x) | ((u32)f2bf(f.y) << 16);
        u32 hi = (u32)f2bf(f.z) | ((u32)f2bf(f.w) << 16);
        ((uint2*)out)[i] = make_uint2(lo, hi);
    }
}

// ---------------------------------------------------------------------------
// fp32 [R,C] -> bf16 [C,R] transpose+convert. Grid (C/64, R/64), block 256.
// ---------------------------------------------------------------------------
__global__ __launch_bounds__(256) void transpose_cvt(const float* __restrict__ in,
                                                     u16* __restrict__ out,
                                                     int R, int C) {
    __shared__ u16 T[64][65];
    const int c0 = blockIdx.x * 64, r0 = blockIdx.y * 64;
    const int tx = threadIdx.x & 63, ty = threadIdx.x >> 6;
#pragma unroll
    for (int p = 0; p < 16; ++p) {
        int rr = p * 4 + ty;
        T[rr][tx] = f2bf(in[(size_t)(r0 + rr) * C + c0 + tx]);
    }
    __syncthreads();
#pragma unroll
    for (int p = 0; p < 16; ++p) {
        int cc = p * 4 + ty;
        out[(size_t)(c0 + cc) * R + r0 + tx] = T[tx][cc];
    }
}

// ---------------------------------------------------------------------------
// v [B*S, :] bf16 -> vt [(b,h), 128, 2048]. Grid (S/64, VD/64, B*NH), block 256.
// ---------------------------------------------------------------------------
__global__ __launch_bounds__(256) void transpose_v(const u16* __restrict__ in, int ldin,
                                                   u16* __restrict__ out) {
    __shared__ u16 T[64][65];
    const int s0 = blockIdx.x * 64, d0 = blockIdx.y * 64;
    const int bh = blockIdx.z, b = bh >> 5, h = bh & 31;
    const int tx = threadIdx.x & 63, ty = threadIdx.x >> 6;
#pragma unroll
    for (int p = 0; p < 16; ++p) {
        int ss = p * 4 + ty;
        T[ss][tx] = in[(size_t)(b * SS + s0 + ss) * ldin + h * 128 + d0 + tx];
    }
    __syncthreads();
#pragma unroll
    for (int p = 0; p < 16; ++p) {
        int dd = p * 4 + ty;
        out[((size_t)bh * 128 + d0 + dd) * SS + s0 + tx] = T[tx][dd];
    }
}

// ---------------------------------------------------------------------------
// bf16 MFMA GEMM: C[M,N] = A[M,K](lda) @ Bt[N,K](ldb)^T.
// 256x256 tile, BK=64, 8 waves (2M x 4N, per-wave 128x64 out).
// LDS: 2 slots (tile parity) x (A 256x64 + B 256x64) = 128 KiB.
// 8 phases per iter (2 K-tiles t,t+1). Phase = {ds-reads || 1 half-tile stage}
// -> s_barrier -> lgkmcnt(0)+sched_barrier(0) -> setprio(1) 16xMFMA setprio(0)
// -> s_barrier.  Region ledger (regions freed at a phase's 2nd barrier, staged
// next phase; slot0 = even tile, slot1 = odd):
//   p1: rd A-R1,B-R1(s0)      stage A-R2(s1)<-A-hi(t+1)   [freed p7 prev iter]
//   p2: rd B-R2(s0)           stage A-R1(s0)<-A-lo(t+2)   [freed p1]
//   p3: rd A-R2(s0)           stage B-R1(s0)<-B-lo(t+2)   [freed p1]
//   p4: --                    stage B-R2(s0)<-B-hi(t+2)   [freed p2]; vmcnt(6)
//   p5: rd A-R1,B-R1(s1)      stage A-R2(s0)<-A-hi(t+2)   [freed p3]
//   p6: rd B-R2(s1)           stage A-R1(s1)<-A-lo(t+3)   [freed p5]
//   p7: rd A-R2(s1)           stage B-R1(s1)<-B-lo(t+3)   [freed p5]
//   p8: --                    stage B-R2(s1)<-B-hi(t+3)   [freed p6]; vmcnt(6)
// vmcnt(6)@p4 publishes tile t+1 (p6..p8 prev + p1); vmcnt(6)@p8 publishes
// tile t+2 (p2..p5). Steady in-flight after each wait = 3 half-tiles = 6 loads.
// Prologue: tile0 full + tile1{A-R1,B-R1,B-R2}, vmcnt(6), barrier. Last iter
// (t+2>=NT): stages p2..p8 skipped, waits drop to vmcnt(0). NT even (all shapes).
// LDS chunk swizzle c ^= (row&7) via pre-swizzled global source (involution).
// MODE 0: fp32 Cf(ldf). MODE 1: bf16 Cb(ldc).
// MODE 3: bf16 Cb full + fp32 Cf for cols >= nsplit.
// ---------------------------------------------------------------------------
#define BARRIER() asm volatile("s_barrier" ::: "memory")
#define LGKM0()                                              \
    asm volatile("s_waitcnt lgkmcnt(0)" ::: "memory");       \
    __builtin_amdgcn_sched_barrier(0)
#define MF16(MO, NO, AA, BB2)                                                     \
    __builtin_amdgcn_s_setprio(1);                                                \
    _Pragma("unroll") for (int m_ = 0; m_ < 4; ++m_)                              \
    _Pragma("unroll") for (int n_ = 0; n_ < 2; ++n_)                              \
    _Pragma("unroll") for (int k_ = 0; k_ < 2; ++k_)                              \
        acc[m_ + (MO)][n_ + (NO)] = __builtin_amdgcn_mfma_f32_16x16x32_bf16(      \
            AA[m_][k_], BB2[n_][k_], acc[m_ + (MO)][n_ + (NO)], 0, 0, 0);         \
    __builtin_amdgcn_s_setprio(0)

template <int MODE>
__global__ __launch_bounds__(512) void gemm_bt(const u16* __restrict__ A, int lda,
                                               const u16* __restrict__ Bt, int ldb,
                                               float* __restrict__ Cf, int ldf,
                                               u16* __restrict__ Cb, int ldc,
                                               int M, int N, int K, int nsplit) {
    __shared__ __align__(16) u16 As[2][256 * 64];   // 64 KiB
    __shared__ __align__(16) u16 Bs[2][256 * 64];   // 64 KiB

    const int tid = threadIdx.x;
    const int bm0 = blockIdx.y * 256, bn0 = blockIdx.x * 256;
    const int w = tid >> 6, lane = tid & 63;
    const int lo = lane & 15, quad = lane >> 4;
    const int lo7 = lane & 7, l8 = lane >> 3;
    const int wm = (w >> 2) * 128, wn = (w & 3) * 64;  // per-wave 128x64 output

    floatx4 acc[8][4];
#pragma unroll
    for (int m = 0; m < 8; ++m)
#pragma unroll
        for (int n = 0; n < 4; ++n) acc[m][n] = (floatx4){0.f, 0.f, 0.f, 0.f};

    const u16* Ab = A + (size_t)bm0 * lda;
    const u16* Bb = Bt + (size_t)bn0 * ldb;
    const int NT = K >> 6;
    const int csw = (lo7 ^ l8) << 3;   // pre-swizzled source chunk (u16 offset)

    // One GLD16 = 64 lanes x 16B = 8 rows x 128B. lane l -> row rb+(l>>3),
    // LDS chunk (l&7); source chunk (l&7)^(l>>3) (rb % 8 == 0 for all bases).
    // A part P half-tile = rows {P*64..P*64+63} u {P*64+128..+191}.
    // B part P half-tile = rows {g*64 + P*32 .. +31} for g=0..3.
    auto STAGE_A = [&](int s, int P, int tau) {
#pragma unroll
        for (int j = 0; j < 2; ++j) {
            const int rb = P * 64 + j * 128 + w * 8;
            GLD16(Ab + (size_t)(rb + l8) * lda + tau * 64 + csw, &As[s][rb * 64 + lane * 8]);
        }
    };
    auto STAGE_B = [&](int s, int P, int tau) {
#pragma unroll
        for (int j = 0; j < 2; ++j) {
            const int rb = (w >> 2) * 64 + (w & 3) * 8 + P * 32 + j * 128;
            GLD16(Bb + (size_t)(rb + l8) * ldb + tau * 64 + csw, &Bs[s][rb * 64 + lane * 8]);
        }
    };
    auto RD_A = [&](short8 (&dst)[4][2], int s, int half) {
#pragma unroll
        for (int m = 0; m < 4; ++m)
#pragma unroll
            for (int ks = 0; ks < 2; ++ks) {
                const int r = wm + half * 64 + m * 16 + lo;
                dst[m][ks] = *(const short8*)&As[s][r * 64 + (((ks * 4 + quad) ^ lo7) << 3)];
            }
    };
    auto RD_B = [&](short8 (&dst)[2][2], int s, int half) {
#pragma unroll
        for (int n = 0; n < 2; ++n)
#pragma unroll
            for (int ks = 0; ks < 2; ++ks) {
                const int r = wn + half * 32 + n * 16 + lo;
                dst[n][ks] = *(const short8*)&Bs[s][r * 64 + (((ks * 4 + quad) ^ lo7) << 3)];
            }
    };

    // prologue: tile0 full (4 half-tiles) + tile1 partial (A-R1,B-R1,B-R2);
    // vmcnt(6) publishes tile0, leaves tile1's 3 half-tiles in flight (steady).
    STAGE_A(0, 0, 0); STAGE_A(0, 1, 0); STAGE_B(0, 0, 0); STAGE_B(0, 1, 0);
    STAGE_A(1, 0, 1); STAGE_B(1, 0, 1); STAGE_B(1, 1, 1);
    asm volatile("s_waitcnt vmcnt(6)" ::: "memory");
    BARRIER();

    for (int t = 0; t < NT; t += 2) {
        const bool full = (t + 2 < NT);
        short8 alo[4][2], ahi[4][2], blo[2][2], bhi[2][2];

        // ---- p1 ----
        RD_A(alo, 0, 0); RD_B(blo, 0, 0);
        STAGE_A(1, 1, t + 1);
        BARRIER(); LGKM0();
        MF16(0, 0, alo, blo);
        BARRIER();
        // ---- p2 ----
        RD_B(bhi, 0, 1);
        if (full) STAGE_A(0, 0, t + 2);
        BARRIER(); LGKM0();
        MF16(0, 2, alo, bhi);
        BARRIER();
        // ---- p3 ----
        RD_A(ahi, 0, 1);
        if (full) STAGE_B(0, 0, t + 2);
        BARRIER(); LGKM0();
        MF16(4, 0, ahi, blo);
        BARRIER();
        // ---- p4 ----
        if (full) {
            STAGE_B(0, 1, t + 2);
            asm volatile("s_waitcnt vmcnt(6)" ::: "memory");
        } else {
            asm volatile("s_waitcnt vmcnt(0)" ::: "memory");
        }
        BARRIER(); LGKM0();
        MF16(4, 2, ahi, bhi);
        BARRIER();
        // ---- p5 ----
        RD_A(alo, 1, 0); RD_B(blo, 1, 0);
        if (full) STAGE_A(0, 1, t + 2);
        BARRIER(); LGKM0();
        MF16(0, 0, alo, blo);
        BARRIER();
        // ---- p6 ----
        RD_B(bhi, 1, 1);
        if (full) STAGE_A(1, 0, t + 3);
        BARRIER(); LGKM0();
        MF16(0, 2, alo, bhi);
        BARRIER();
        // ---- p7 ----
        RD_A(ahi, 1, 1);
        if (full) STAGE_B(1, 0, t + 3);
        BARRIER(); LGKM0();
        MF16(4, 0, ahi, blo);
        BARRIER();
        // ---- p8 ----
        if (full) {
            STAGE_B(1, 1, t + 3);
            asm volatile("s_waitcnt vmcnt(6)" ::: "memory");
        } else {
            asm volatile("s_waitcnt vmcnt(0)" ::: "memory");
        }
        BARRIER(); LGKM0();
        MF16(4, 2, ahi, bhi);
        BARRIER();
    }

#pragma unroll
    for (int m = 0; m < 8; ++m) {
#pragma unroll
        for (int n = 0; n < 4; ++n) {
            const int row = bm0 + wm + m * 16 + quad * 4;
            const int col = bn0 + wn + n * 16 + lo;
#pragma unroll
            for (int r = 0; r < 4; ++r) {
                float v = acc[m][n][r];
                if (MODE == 0) Cf[(size_t)(row + r) * ldf + col] = v;
                if (MODE == 1) Cb[(size_t)(row + r) * ldc + col] = f2bf(v);
                if (MODE == 3) {
                    Cb[(size_t)(row + r) * ldc + col] = f2bf(v);
                    if (col >= nsplit) Cf[(size_t)(row + r) * ldf + (col - nsplit)] = v;
                }
            }
        }
    }
}

// ---------------------------------------------------------------------------
// MFMA flash attention (causal), Q-tile 128 rows/block (wave owns 32 rows),
// K-tile 64 keys. Single-pass softmax (scores bounded; no max shift),
// l computed via 16 ones-columns appended to V^T (pure MFMA, no shuffles).
// Staging via global_load_lds (linear dest, pre-swizzled source); K(kt+1)
// prefetch under PV, V(kt+1) prefetch under next QK+softmax.
// Grid (64, 16): x=bh (same-bh blocks on same XCD), y=qt reversed.
// ---------------------------------------------------------------------------
__global__ __launch_bounds__(256) void mla_attn_mfma(const u16* __restrict__ qm,
                                                     const u16* __restrict__ km, int ldk,
                                                     const u16* __restrict__ vt,
                                                     u16* __restrict__ ao) {
    __shared__ __align__(16) u16 Ks[64 * 128];        // [key][hd], chunk ^= key&15
    __shared__ __align__(16) u16 Vt[(128 + 16) * 64]; // [vd][key], chunk ^= vd&7; rows 128..143 = 1.0
    __shared__ __align__(16) u16 Ps[128 * 68];        // [q][key], stride 68 (conflict-free)

    const int qt = 15 - blockIdx.y;  // reversed: longest blocks dispatch first
    const int bh = blockIdx.x;
    const int b = bh >> 5, h = bh & 31;
    const int tid = threadIdx.x;
    const int w = tid >> 6, lane = tid & 63;
    const int lo = lane & 15, quad = lane >> 4;
    const int q0 = qt * 128;

    const float SCALE_L2E = 0.08838834764831845f * 1.4426950408889634f;

    // ones rows (vd 128..143) for the l-column trick: 16*64 u16 = 512 u32
    {
        u32* p = (u32*)&Vt[128 * 64];
        for (int i = tid; i < 512; i += 256) p[i] = 0x3F803F80u;
    }

    const u16* kbase = km + (size_t)(b * SS) * ldk + h * 128;
    const u16* vtbase = vt + (size_t)bh * 128 * SS;
    const int nkt = 2 * qt + 2;

    // per-thread staging constants: linear LDS dest (o bytes), pre-swizzled
    // global source offsets (XOR involution == the read-side swizzle)
    int ol_[4], kgo[4], vgo[4];
#pragma unroll
    for (int p = 0; p < 4; ++p) {
        int o = tid * 16 + p * 4096;           // byte offset within 16KB tile
        int key = o >> 8, ch = (o & 255) >> 4; // K row, 16B chunk
        kgo[p] = key * ldk + ((ch ^ (key & 15)) << 3);
        int d = o >> 7, ch2 = (o & 127) >> 4;  // V row, 16B chunk
        vgo[p] = d * SS + ((ch2 ^ (d & 7)) << 3);
        ol_[p] = o >> 1;                       // u16 index (linear LDS)
    }

    // prologue: stage tile 0 (K and V) directly to LDS
#pragma unroll
    for (int p = 0; p < 4; ++p) GLD16(kbase + kgo[p], &Ks[ol_[p]]);
#pragma unroll
    for (int p = 0; p < 4; ++p) GLD16(vtbase + vgo[p], &Vt[ol_[p]]);

    // Q fragments: wave w owns q rows w*32 + mf*16 + lo
    short8 qf[2][4];
#pragma unroll
    for (int mf = 0; mf < 2; ++mf) {
        const u16* qrow = qm + (size_t)(b * SS + q0 + w * 32 + mf * 16 + lo) * HH + h * 128;
#pragma unroll
        for (int ks = 0; ks < 4; ++ks) qf[mf][ks] = *(const short8*)(qrow + ks * 32 + quad * 8);
    }

    floatx4 oacc[2][8], olv[2];
#pragma unroll
    for (int mf = 0; mf < 2; ++mf) {
        olv[mf] = (floatx4){0.f, 0.f, 0.f, 0.f};
#pragma unroll
        for (int n = 0; n < 8; ++n) oacc[mf][n] = (floatx4){0.f, 0.f, 0.f, 0.f};
    }

    __syncthreads();  // tile 0 staged (embedded vmcnt(0) drains the GLDs)

    for (int kt = 0; kt < nkt; ++kt) {
        const bool need_mask = (kt >= nkt - 2);
        const bool notlast = (kt + 1 < nkt);

        // ---- QK^T + softmax -> Ps (reads Ks only) ----
#pragma unroll
        for (int mf = 0; mf < 2; ++mf) {
            floatx4 s[4];
#pragma unroll
            for (int nf = 0; nf < 4; ++nf) s[nf] = (floatx4){0.f, 0.f, 0.f, 0.f};
            __builtin_amdgcn_s_setprio(1);
#pragma unroll
            for (int nf = 0; nf < 4; ++nf)
#pragma unroll
                for (int ks = 0; ks < 4; ++ks) {
                    short8 kf = *(const short8*)&Ks[(nf * 16 + lo) * 128 + (((ks * 4 + quad) ^ lo) << 3)];
                    s[nf] = __builtin_amdgcn_mfma_f32_16x16x32_bf16(qf[mf][ks], kf, s[nf], 0, 0, 0);
                }
            __builtin_amdgcn_s_setprio(0);
            // P = exp2(s*scale) (bounded scores: no max shift), masked -> 0
#pragma unroll
            for (int nf = 0; nf < 4; ++nf)
#pragma unroll
                for (int r = 0; r < 4; ++r) {
                    float p = fast_exp2(s[nf][r] * SCALE_L2E);
                    if (need_mask) {
                        int kgi = kt * 64 + nf * 16 + lo;
                        int qg = q0 + w * 32 + mf * 16 + quad * 4 + r;
                        p = (kgi <= qg) ? p : 0.f;
                    }
                    Ps[(w * 32 + mf * 16 + quad * 4 + r) * 68 + nf * 16 + lo] = f2bf(p);
                }
        }

        __syncthreads();  // all waves done reading Ks; drains V(kt) prefetch too

        // prefetch K(kt+1) into Ks — lands under the PV phase below
        if (notlast) {
            const u16* kn = kbase + (size_t)(kt + 1) * 64 * ldk;
#pragma unroll
            for (int p = 0; p < 4; ++p) GLD16(kn + kgo[p], &Ks[ol_[p]]);
        }

        // ---- PV + l (reads Vt + own Ps rows; same-wave Ps dep only) ----
#pragma unroll
        for (int mf = 0; mf < 2; ++mf) {
            short8 pa[2];
#pragma unroll
            for (int ks2 = 0; ks2 < 2; ++ks2)
                pa[ks2] = *(const short8*)&Ps[(w * 32 + mf * 16 + lo) * 68 + ks2 * 32 + quad * 8];
            __builtin_amdgcn_s_setprio(1);
#pragma unroll
            for (int n = 0; n < 8; ++n)
#pragma unroll
                for (int ks2 = 0; ks2 < 2; ++ks2) {
                    short8 vf = *(const short8*)&Vt[(n * 16 + lo) * 64 + (((ks2 * 4 + quad) ^ (lo & 7)) << 3)];
                    oacc[mf][n] = __builtin_amdgcn_mfma_f32_16x16x32_bf16(pa[ks2], vf, oacc[mf][n], 0, 0, 0);
                }
#pragma unroll
            for (int ks2 = 0; ks2 < 2; ++ks2) {
                short8 vf = *(const short8*)&Vt[(128 + lo) * 64 + (((ks2 * 4 + quad) ^ (lo & 7)) << 3)];
                olv[mf] = __builtin_amdgcn_mfma_f32_16x16x32_bf16(pa[ks2], vf, olv[mf], 0, 0, 0);
            }
            __builtin_amdgcn_s_setprio(0);
        }

        __syncthreads();  // all waves done reading Vt; drains K(kt+1) prefetch

        // prefetch V(kt+1) into Vt — lands under the next QK+softmax phase
        if (notlast) {
            const u16* vn = vtbase + (size_t)(kt + 1) * 64;
#pragma unroll
            for (int p = 0; p < 4; ++p) GLD16(vn + vgo[p], &Vt[ol_[p]]);
        }
    }

    // epilogue: O / l
#pragma unroll
    for (int mf = 0; mf < 2; ++mf) {
        u16* obase = ao + (size_t)(b * SS + q0 + w * 32 + mf * 16 + quad * 4) * HH + h * 128;
#pragma unroll
        for (int r = 0; r < 4; ++r) {
            float inv = 1.f / olv[mf][r];
#pragma unroll
            for (int n = 0; n < 8; ++n)
                obase[(size_t)r * HH + n * 16 + lo] = f2bf(oacc[mf][n][r] * inv);
        }
    }
}

// ---------------------------------------------------------------------------
// Orchestration. ws layout (u16 elements):
//   hs_bf @0 (16.8M)            -> vt aliases after GF1
//   q_bf @16777216 (16.8M)
//   kv_bf @33554432 (33.55M)    [4096][8192]: k cols 0..4095, v cols 4096..8191
//   ao_bf @67108864 (16.8M)
//   wqa_kvaT @83886080 (8.39M)  [2048][4096]: w_qaT rows 0..1535, w_kvaT rows 1536..2047
//   w_qbT @92274688 (6.29M)
//   wkv_bT @98566144 (4.19M)    [8192][512]: w_kbT rows 0..4095, w_vbT rows 4096..8191
//   w_oT @102760448 (16.8M)
//   qc_ckv @119537664 (8.39M)   [4096][2048]: q_c cols 0..1535, ckv cols 1536..2047
// Total 255.9 MB.
// ---------------------------------------------------------------------------
extern "C" void kernel_launch(void* const* d_in, const int* in_sizes, int n_in,
                              void* d_out, int out_size, void* d_ws, size_t ws_size,
                              hipStream_t stream) {
    const float* hs    = (const float*)d_in[0];
    const float* w_qa  = (const float*)d_in[1];
    const float* w_qb  = (const float*)d_in[2];
    const float* w_kva = (const float*)d_in[3];
    const float* w_kb  = (const float*)d_in[4];
    const float* w_vb  = (const float*)d_in[5];
    const float* w_o   = (const float*)d_in[6];

    float* out   = (float*)d_out;
    float* ckv_f = out + (size_t)MROWS * HH;

    u16* ws = (u16*)d_ws;
    u16* hs_bf    = ws;
    u16* vt       = ws;                       // aliases hs_bf (dead after GF1)
    u16* q_bf     = ws + 16777216ull;
    u16* kv_bf    = ws + 33554432ull;         // [4096][8192]
    u16* ao_bf    = ws + 67108864ull;
    u16* wqa_kvaT = ws + 83886080ull;         // [2048][4096]
    u16* w_qbT    = ws + 92274688ull;
    u16* wkv_bT   = ws + 98566144ull;         // [8192][512]
    u16* w_oT     = ws + 102760448ull;
    u16* qc_ckv   = ws + 119537664ull;        // [4096][2048]

    dim3 blk(256);
    dim3 blkg(512);

    cvt_bf16<<<2048, blk, 0, stream>>>(hs, hs_bf, (MROWS * HH) / 4);
    transpose_cvt<<<dim3(QRANK / 64, HH / 64), blk, 0, stream>>>(w_qa, wqa_kvaT, HH, QRANK);
    transpose_cvt<<<dim3(KVRANK / 64, HH / 64), blk, 0, stream>>>(w_kva, wqa_kvaT + 1536ull * 4096, HH, KVRANK);
    transpose_cvt<<<dim3(HH / 64, QRANK / 64), blk, 0, stream>>>(w_qb, w_qbT, QRANK, HH);
    transpose_cvt<<<dim3(HH / 64, KVRANK / 64), blk, 0, stream>>>(w_kb, wkv_bT, KVRANK, HH);
    transpose_cvt<<<dim3(HH / 64, KVRANK / 64), blk, 0, stream>>>(w_vb, wkv_bT + 4096ull * 512, KVRANK, HH);
    transpose_cvt<<<dim3(HH / 64, HH / 64), blk, 0, stream>>>(w_o, w_oT, HH, HH);

    // GF1: [q_c | ckv] = hs @ [w_qa | w_kva]   (N=2048, K=4096); ckv also fp32->d_out
    gemm_bt<3><<<dim3(2048 / 256, MROWS / 256), blkg, 0, stream>>>(
        hs_bf, HH, wqa_kvaT, HH, ckv_f, KVRANK, qc_ckv, 2048, MROWS, 2048, HH, QRANK);
    // G2: q = q_c @ w_qb   (K=1536, A lda=2048)
    gemm_bt<1><<<dim3(HH / 256, MROWS / 256), blkg, 0, stream>>>(
        qc_ckv, 2048, w_qbT, QRANK, nullptr, 0, q_bf, HH, MROWS, HH, QRANK, 0);
    // GKV: [k | v] = ckv @ [w_kb | w_vb]   (N=8192, K=512, A lda=2048)
    gemm_bt<1><<<dim3(8192 / 256, MROWS / 256), blkg, 0, stream>>>(
        qc_ckv + 1536, 2048, wkv_bT, KVRANK, nullptr, 0, kv_bf, 8192, MROWS, 8192, KVRANK, 0);
    // V^T per head (vt aliases dead hs_bf)
    transpose_v<<<dim3(SS / 64, VDIM / 64, BB * NHEADS), blk, 0, stream>>>(kv_bf + 4096, 8192, vt);
    // causal MFMA attention: grid (bh, qt) — longest-first, same-bh on same XCD
    mla_attn_mfma<<<dim3(BB * NHEADS, 16), blk, 0, stream>>>(q_bf, kv_bf, 8192, vt, ao_bf);
    // G7: out = ao @ w_o
    gemm_bt<0><<<dim3(HH / 256, MROWS / 256), blkg, 0, stream>>>(
        ao_bf, HH, w_oT, HH, out, HH, nullptr, 0, MROWS, HH, HH, 0);
}